// Round 4
// baseline (828.454 us; speedup 1.0000x reference)
//
#include <hip/hip_runtime.h>

// MHA forward: B=2, S=4096, H=12, HD=64, D=768. f32 in/out, bf16 MFMA compute.
// Pipeline: cvt(x,W)->bf16 | GEMM qkv (Q pre-scaled by 0.125*log2e) -> Q,K,V
//           | flash attn (8 waves, split-K in-block, exp2-domain softmax,
//             defer-max, in-LDS merge) -> ctx bf16 | GEMM out -> f32.

#define S_LEN 4096
#define NHEAD 12
#define NEGB2 (-1.442695e9f)   // -1e9 * log2(e): mask bias in log2 domain
#define THR2 11.541561f        // defer-max threshold: 8 nats in log2
#define QSCALE 0.18033688f     // 0.125 * log2(e)

typedef __attribute__((ext_vector_type(8))) short short8;
typedef __attribute__((ext_vector_type(4))) float f32x4;
typedef __attribute__((ext_vector_type(4))) int i32x4;

__device__ __forceinline__ unsigned short f2bf(float f) {
  unsigned u = __builtin_bit_cast(unsigned, f);
  u += 0x7fffu + ((u >> 16) & 1u);   // round-to-nearest-even
  return (unsigned short)(u >> 16);
}

__device__ __forceinline__ f32x4 mfma_bf16(short8 a, short8 b, f32x4 c) {
  return __builtin_amdgcn_mfma_f32_16x16x32_bf16(a, b, c, 0, 0, 0);
}

// ---------------- f32 -> bf16 convert, 8 elems/thread ----------------
__global__ __launch_bounds__(256) void cvt_kernel(const float* __restrict__ in,
                                                  unsigned short* __restrict__ out,
                                                  int n8) {
  int i = blockIdx.x * blockDim.x + threadIdx.x;
  int stride = gridDim.x * blockDim.x;
  for (; i < n8; i += stride) {
    float4 a = ((const float4*)in)[i * 2];
    float4 b = ((const float4*)in)[i * 2 + 1];
    short8 r;
    r[0] = (short)f2bf(a.x); r[1] = (short)f2bf(a.y);
    r[2] = (short)f2bf(a.z); r[3] = (short)f2bf(a.w);
    r[4] = (short)f2bf(b.x); r[5] = (short)f2bf(b.y);
    r[6] = (short)f2bf(b.z); r[7] = (short)f2bf(b.w);
    ((short8*)out)[i] = r;
  }
}

// ---------------- GEMM: C = A * Bm^T (+bias). 128x128 tile, BK=32 ----------------
template <int EPI>
__global__ __launch_bounds__(256)
void gemm_bt(const unsigned short* __restrict__ A, const unsigned short* __restrict__ Bm,
             int K,
             const float* __restrict__ bias0, const float* __restrict__ bias1,
             const float* __restrict__ bias2,
             unsigned short* __restrict__ qkv_out, float* __restrict__ f_out) {
  __shared__ short As[128][40];
  __shared__ short Bs[128][40];
  const int n0 = blockIdx.x * 128;
  const int m0 = blockIdx.y * 128;
  const int t = threadIdx.x;
  const int lane = t & 63;
  const int w = t >> 6, wm = w >> 1, wn = w & 1;
  const int sr = t >> 2, sc = (t & 3) * 8;
  const unsigned short* ga = A + (m0 + sr) * K + sc;
  const unsigned short* gb = Bm + (n0 + sr) * K + sc;
  f32x4 acc[4][4] = {};
  for (int kt = 0; kt < K; kt += 32) {
    short8 a0 = *(const short8*)(ga + kt);
    short8 a1 = *(const short8*)(ga + kt + 64 * K);
    short8 b0 = *(const short8*)(gb + kt);
    short8 b1 = *(const short8*)(gb + kt + 64 * K);
    __syncthreads();
    *(short8*)&As[sr][sc] = a0;
    *(short8*)&As[sr + 64][sc] = a1;
    *(short8*)&Bs[sr][sc] = b0;
    *(short8*)&Bs[sr + 64][sc] = b1;
    __syncthreads();
    short8 af[4], bfr[4];
#pragma unroll
    for (int i = 0; i < 4; i++) {
      af[i]  = *(const short8*)&As[wm * 64 + i * 16 + (lane & 15)][(lane >> 4) * 8];
      bfr[i] = *(const short8*)&Bs[wn * 64 + i * 16 + (lane & 15)][(lane >> 4) * 8];
    }
#pragma unroll
    for (int mi = 0; mi < 4; mi++)
#pragma unroll
      for (int ni = 0; ni < 4; ni++)
        acc[mi][ni] = mfma_bf16(af[mi], bfr[ni], acc[mi][ni]);
  }
  if constexpr (EPI == 0) {
    const int tix = n0 / 768;
    const float* bias = (tix == 0) ? bias0 : (tix == 1) ? bias1 : bias2;
    const float qs = (tix == 0) ? QSCALE : 1.0f;   // pre-scale Q into log2 domain
    unsigned short* dst = qkv_out + tix * (2 * NHEAD * S_LEN * 64);
#pragma unroll
    for (int mi = 0; mi < 4; mi++) {
      const int r0 = m0 + wm * 64 + mi * 16 + ((lane >> 4) << 2);
#pragma unroll
      for (int ni = 0; ni < 4; ni++) {
        const int jr = (n0 - tix * 768) + wn * 64 + ni * 16 + (lane & 15);
        const int h = jr >> 6, d = jr & 63;
        const float bv = bias[jr];
#pragma unroll
        for (int reg = 0; reg < 4; reg++) {
          const int r = r0 + reg;
          const int b = r >> 12, s = r & (S_LEN - 1);
          dst[(((b * NHEAD + h) * S_LEN + s) << 6) + d] = f2bf((acc[mi][ni][reg] + bv) * qs);
        }
      }
    }
  } else {
#pragma unroll
    for (int mi = 0; mi < 4; mi++) {
      const int r0 = m0 + wm * 64 + mi * 16 + ((lane >> 4) << 2);
#pragma unroll
      for (int ni = 0; ni < 4; ni++) {
        const int gc = n0 + wn * 64 + ni * 16 + (lane & 15);
        const float bv = bias0[gc];
#pragma unroll
        for (int reg = 0; reg < 4; reg++)
          f_out[(r0 + reg) * 768 + gc] = acc[mi][ni][reg] + bv;
      }
    }
  }
}

// ---------------- flash attention (swapped QK^T, split-K in-block) ----------------
// grid (S/128, B*H), 512 thr = 8 waves. Waves 0-3: keys [0,2048); 4-7: [2048,4096).
// Each wave owns 32 q-rows (2 qi). Partials merged in LDS at the end.
union ShMem {
  short kv[2][2][64][72];   // [z][K=0/V=1][row][col(+pad)]  = 36864 B
  float mg[9216];           // merge: o[256][32] (XOR-swz) + ml[256][4] at 8192
};

__global__ __launch_bounds__(512, 5)
void attn_kernel(const unsigned short* __restrict__ Q, const unsigned short* __restrict__ Km,
                 const unsigned short* __restrict__ V, const int* __restrict__ mask,
                 unsigned short* __restrict__ ctx) {
  __shared__ ShMem sh;
  const int qt = blockIdx.x;
  const int bh = blockIdx.y;
  const int b = bh / NHEAD, h = bh % NHEAD;
  const unsigned short* Qb = Q + bh * (S_LEN * 64);
  const unsigned short* Kb = Km + bh * (S_LEN * 64);
  const unsigned short* Vb = V + bh * (S_LEN * 64);
  const int* mb = mask + b * S_LEN;
  const int t = threadIdx.x, lane = t & 63, w = t >> 6;
  const int z = w >> 2, wq = w & 3, tz = t & 255;
  const int c = lane & 15, g = lane >> 4;
  const int q0 = qt * 128 + wq * 32;
  const int kbase = z * 2048;
  short (*Ks)[72] = sh.kv[z][0];
  short (*Vt)[72] = sh.kv[z][1];

  // Q as QKT/PV B-operand: qf[qi][kk] = Q[q0+qi*16+c][kk*32+g*8 ..+8] (pre-scaled)
  short8 qf[2][2];
#pragma unroll
  for (int qi = 0; qi < 2; qi++)
#pragma unroll
    for (int kk = 0; kk < 2; kk++)
      qf[qi][kk] = *(const short8*)(Qb + (q0 + qi * 16 + c) * 64 + kk * 32 + g * 8);

  f32x4 oacc[4][2] = {};          // O^T frag: [dmi][qi], reg r -> d=16dmi+4g+r, q=16qi+c
  float mrun[2], lrun[2];
  mrun[0] = mrun[1] = -__builtin_inff();
  lrun[0] = lrun[1] = 0.f;

  const int sr = tz >> 3, sc = (tz & 7) * 8;   // staging within z-group: full 64x64
  const int swzw = (tz & 7) << 3;              // Vt write swizzle ((d>>3)<<3)
  const int idx_a = c + 32 * (g & 1);          // bpermute sources for PV B-frag
  const int idx_b = idx_a + 16;
  const bool hi_sel = (lane >= 32);

  for (int k0 = kbase; k0 < kbase + 2048; k0 += 64) {
    short8 kv0 = *(const short8*)(Kb + (k0 + sr) * 64 + sc);
    short8 kv1 = *(const short8*)(Kb + (k0 + sr + 32) * 64 + sc);
    short8 vv0 = *(const short8*)(Vb + (k0 + sr) * 64 + sc);
    short8 vv1 = *(const short8*)(Vb + (k0 + sr + 32) * 64 + sc);
    __syncthreads();
    *(short8*)&Ks[sr][sc] = kv0;
    *(short8*)&Ks[sr + 32][sc] = kv1;
#pragma unroll
    for (int j = 0; j < 8; j++) {
      Vt[sc + j][sr ^ swzw] = vv0[j];
      Vt[sc + j][(sr + 32) ^ swzw] = vv1[j];
    }
    __syncthreads();

    // S2^T = K Q2^T (already in log2 domain via Q pre-scale)
    f32x4 st[2][4];
    __builtin_amdgcn_s_setprio(1);
#pragma unroll
    for (int mi = 0; mi < 4; mi++) {
      short8 ka0 = *(const short8*)&Ks[mi * 16 + c][g * 8];
      short8 ka1 = *(const short8*)&Ks[mi * 16 + c][32 + g * 8];
#pragma unroll
      for (int qi = 0; qi < 2; qi++) {
        f32x4 zz = {0.f, 0.f, 0.f, 0.f};
        zz = mfma_bf16(ka0, qf[qi][0], zz);
        zz = mfma_bf16(ka1, qf[qi][1], zz);
        st[qi][mi] = zz;
      }
    }
    __builtin_amdgcn_s_setprio(0);
    // additive mask bias (per-key, amortized over qi); key = k0+16mi+4g+r
    f32x4 maskb[4];
#pragma unroll
    for (int mi = 0; mi < 4; mi++) {
      i32x4 mk = *(const i32x4*)(mb + k0 + 16 * mi + 4 * g);
#pragma unroll
      for (int r = 0; r < 4; r++) maskb[mi][r] = (mk[r] == 0) ? NEGB2 : 0.f;
    }
#pragma unroll
    for (int qi = 0; qi < 2; qi++)
#pragma unroll
      for (int mi = 0; mi < 4; mi++)
#pragma unroll
        for (int r = 0; r < 4; r++) st[qi][mi][r] += maskb[mi][r];
    // row max (in-register + cross-group shfl)
    float pm[2];
#pragma unroll
    for (int qi = 0; qi < 2; qi++) {
      float x = st[qi][0][0];
#pragma unroll
      for (int mi = 0; mi < 4; mi++)
#pragma unroll
        for (int r = 0; r < 4; r++) x = fmaxf(x, st[qi][mi][r]);
      x = fmaxf(x, __shfl_xor(x, 16));
      x = fmaxf(x, __shfl_xor(x, 32));
      pm[qi] = x;
    }
    // defer-max (T13): rescale only when max grew past THR2 (wave-uniform branch)
    if (!__all((pm[0] <= mrun[0] + THR2) && (pm[1] <= mrun[1] + THR2))) {
#pragma unroll
      for (int qi = 0; qi < 2; qi++) {
        float mnew = fmaxf(mrun[qi], pm[qi]);
        float al = __builtin_amdgcn_exp2f(mrun[qi] - mnew);
        mrun[qi] = mnew;
        lrun[qi] *= al;
#pragma unroll
        for (int dmi = 0; dmi < 4; dmi++)
#pragma unroll
          for (int r = 0; r < 4; r++) oacc[dmi][qi][r] *= al;
      }
    }
    // P = exp2(st - m), row-sum
#pragma unroll
    for (int qi = 0; qi < 2; qi++) {
      float ps = 0.f;
#pragma unroll
      for (int mi = 0; mi < 4; mi++)
#pragma unroll
        for (int r = 0; r < 4; r++) {
          float p = __builtin_amdgcn_exp2f(st[qi][mi][r] - mrun[qi]);
          st[qi][mi][r] = p;
          ps += p;
        }
      ps += __shfl_xor(ps, 16);
      ps += __shfl_xor(ps, 32);
      lrun[qi] += ps;
    }
    // pack P to bf16 pairs
    unsigned uu[2][4][2];
#pragma unroll
    for (int qi = 0; qi < 2; qi++)
#pragma unroll
      for (int mi = 0; mi < 4; mi++) {
        asm("v_cvt_pk_bf16_f32 %0, %1, %2"
            : "=v"(uu[qi][mi][0]) : "v"(st[qi][mi][0]), "v"(st[qi][mi][1]));
        asm("v_cvt_pk_bf16_f32 %0, %1, %2"
            : "=v"(uu[qi][mi][1]) : "v"(st[qi][mi][2]), "v"(st[qi][mi][3]));
      }
    // PV: O^T += Vt . P^T
#pragma unroll
    for (int kk = 0; kk < 2; kk++) {
      short8 pb[2];
#pragma unroll
      for (int qi = 0; qi < 2; qi++) {
        int a0 = __shfl((int)uu[qi][2 * kk][0], idx_a);
        int b0 = __shfl((int)uu[qi][2 * kk + 1][0], idx_a);
        int a1 = __shfl((int)uu[qi][2 * kk][1], idx_a);
        int b1 = __shfl((int)uu[qi][2 * kk + 1][1], idx_a);
        int a2 = __shfl((int)uu[qi][2 * kk][0], idx_b);
        int b2 = __shfl((int)uu[qi][2 * kk + 1][0], idx_b);
        int a3 = __shfl((int)uu[qi][2 * kk][1], idx_b);
        int b3 = __shfl((int)uu[qi][2 * kk + 1][1], idx_b);
        i32x4 dw;
        dw[0] = hi_sel ? b0 : a0;
        dw[1] = hi_sel ? b1 : a1;
        dw[2] = hi_sel ? b2 : a2;
        dw[3] = hi_sel ? b3 : a3;
        pb[qi] = __builtin_bit_cast(short8, dw);
      }
      __builtin_amdgcn_s_setprio(1);
#pragma unroll
      for (int dmi = 0; dmi < 4; dmi++) {
        const int hsw = ((2 * dmi + (c >> 3)) & 7) << 3;
        short8 vf = *(const short8*)&Vt[16 * dmi + c][(32 * kk + 8 * g) ^ hsw];
        oacc[dmi][0] = mfma_bf16(vf, pb[0], oacc[dmi][0]);
        oacc[dmi][1] = mfma_bf16(vf, pb[1], oacc[dmi][1]);
      }
      __builtin_amdgcn_s_setprio(0);
    }
  }

  // -------- in-LDS merge of the two K-halves --------
  __syncthreads();   // all tiles done; kv region free for reuse
  if (z == 1) {
#pragma unroll
    for (int dmi = 0; dmi < 4; dmi++)
#pragma unroll
      for (int qi = 0; qi < 2; qi++)
        *(f32x4*)&sh.mg[tz * 32 + ((dmi * 2 + qi) ^ (tz & 7)) * 4] = oacc[dmi][qi];
    f32x4 mlv = {mrun[0], mrun[1], lrun[0], lrun[1]};
    *(f32x4*)&sh.mg[8192 + tz * 4] = mlv;
  }
  __syncthreads();
  if (z == 0) {
    f32x4 ml1 = *(const f32x4*)&sh.mg[8192 + tz * 4];
    float a0s[2], a1s[2], inv[2];
#pragma unroll
    for (int qi = 0; qi < 2; qi++) {
      float m1 = ml1[qi], l1 = ml1[2 + qi];
      float mm = fmaxf(mrun[qi], m1);
      a0s[qi] = __builtin_amdgcn_exp2f(mrun[qi] - mm);
      a1s[qi] = __builtin_amdgcn_exp2f(m1 - mm);
      inv[qi] = 1.0f / (lrun[qi] * a0s[qi] + l1 * a1s[qi]);
    }
#pragma unroll
    for (int qi = 0; qi < 2; qi++) {
      const int row = q0 + qi * 16 + c;
#pragma unroll
      for (int dmi = 0; dmi < 4; dmi++) {
        f32x4 o1 = *(const f32x4*)&sh.mg[tz * 32 + ((dmi * 2 + qi) ^ (tz & 7)) * 4];
        float x0 = (oacc[dmi][qi][0] * a0s[qi] + o1[0] * a1s[qi]) * inv[qi];
        float x1 = (oacc[dmi][qi][1] * a0s[qi] + o1[1] * a1s[qi]) * inv[qi];
        float x2 = (oacc[dmi][qi][2] * a0s[qi] + o1[2] * a1s[qi]) * inv[qi];
        float x3 = (oacc[dmi][qi][3] * a0s[qi] + o1[3] * a1s[qi]) * inv[qi];
        unsigned p0, p1;
        asm("v_cvt_pk_bf16_f32 %0, %1, %2" : "=v"(p0) : "v"(x0), "v"(x1));
        asm("v_cvt_pk_bf16_f32 %0, %1, %2" : "=v"(p1) : "v"(x2), "v"(x3));
        uint2 u2v; u2v.x = p0; u2v.y = p1;
        *(uint2*)&ctx[(size_t)(b * S_LEN + row) * 768 + h * 64 + 16 * dmi + 4 * g] = u2v;
      }
    }
  }
}

// ---------------- launch ----------------
extern "C" void kernel_launch(void* const* d_in, const int* in_sizes, int n_in,
                              void* d_out, int out_size, void* d_ws, size_t ws_size,
                              hipStream_t stream) {
  const float* x  = (const float*)d_in[0];
  const int* mask = (const int*)d_in[1];
  const float* Wq = (const float*)d_in[2];
  const float* bq = (const float*)d_in[3];
  const float* Wk = (const float*)d_in[4];
  const float* bk = (const float*)d_in[5];
  const float* Wv = (const float*)d_in[6];
  const float* bv = (const float*)d_in[7];
  const float* Wo = (const float*)d_in[8];
  const float* bo = (const float*)d_in[9];
  float* out = (float*)d_out;

  const int NE = 8192 * 768;
  const int WE = 768 * 768;
  unsigned short* ws   = (unsigned short*)d_ws;
  unsigned short* xb   = ws;               // x bf16 [8192][768]
  unsigned short* wqkv = xb + NE;          // [2304][768]
  unsigned short* wob  = wqkv + 3 * WE;    // [768][768]
  unsigned short* qb   = wob + WE;         // Q|K|V each [24][4096][64]
  unsigned short* ctxb = qb + 3 * NE;      // ctx bf16 [8192][768]

  cvt_kernel<<<dim3(2048), 256, 0, stream>>>(x, xb, NE / 8);
  cvt_kernel<<<dim3(288), 256, 0, stream>>>(Wq, wqkv, WE / 8);
  cvt_kernel<<<dim3(288), 256, 0, stream>>>(Wk, wqkv + WE, WE / 8);
  cvt_kernel<<<dim3(288), 256, 0, stream>>>(Wv, wqkv + 2 * WE, WE / 8);
  cvt_kernel<<<dim3(288), 256, 0, stream>>>(Wo, wob, WE / 8);

  gemm_bt<0><<<dim3(18, 64), 256, 0, stream>>>(xb, wqkv, 768, bq, bk, bv, qb, nullptr);
  attn_kernel<<<dim3(32, 24), 512, 0, stream>>>(qb, qb + NE, qb + 2 * NE, mask, ctxb);
  gemm_bt<1><<<dim3(6, 64), 256, 0, stream>>>(ctxb, wob, 768, bo, nullptr, nullptr,
                                              nullptr, out);
}

// Round 5
// 429.215 us; speedup vs baseline: 1.9302x; 1.9302x over previous
//
#include <hip/hip_runtime.h>

// MHA forward: B=2, S=4096, H=12, HD=64, D=768. f32 in/out, bf16 MFMA compute.
// Pipeline: cvt(x,W)->bf16 | GEMM qkv (Q pre-scaled by 0.125*log2e) -> Q,K,V
//           | flash attn (8 waves, split-K in-block, exp2-domain softmax,
//             defer-max, in-LDS merge) -> ctx bf16 | GEMM out -> f32.

#define S_LEN 4096
#define NHEAD 12
#define NEGB2 (-1.442695e9f)   // -1e9 * log2(e): mask bias in log2 domain
#define THR2 11.541561f        // defer-max threshold: 8 nats in log2
#define QSCALE 0.18033688f     // 0.125 * log2(e)

typedef __attribute__((ext_vector_type(8))) short short8;
typedef __attribute__((ext_vector_type(4))) float f32x4;
typedef __attribute__((ext_vector_type(4))) int i32x4;

__device__ __forceinline__ unsigned short f2bf(float f) {
  unsigned u = __builtin_bit_cast(unsigned, f);
  u += 0x7fffu + ((u >> 16) & 1u);   // round-to-nearest-even
  return (unsigned short)(u >> 16);
}

__device__ __forceinline__ f32x4 mfma_bf16(short8 a, short8 b, f32x4 c) {
  return __builtin_amdgcn_mfma_f32_16x16x32_bf16(a, b, c, 0, 0, 0);
}

// ---------------- f32 -> bf16 convert, 8 elems/thread ----------------
__global__ __launch_bounds__(256) void cvt_kernel(const float* __restrict__ in,
                                                  unsigned short* __restrict__ out,
                                                  int n8) {
  int i = blockIdx.x * blockDim.x + threadIdx.x;
  int stride = gridDim.x * blockDim.x;
  for (; i < n8; i += stride) {
    float4 a = ((const float4*)in)[i * 2];
    float4 b = ((const float4*)in)[i * 2 + 1];
    short8 r;
    r[0] = (short)f2bf(a.x); r[1] = (short)f2bf(a.y);
    r[2] = (short)f2bf(a.z); r[3] = (short)f2bf(a.w);
    r[4] = (short)f2bf(b.x); r[5] = (short)f2bf(b.y);
    r[6] = (short)f2bf(b.z); r[7] = (short)f2bf(b.w);
    ((short8*)out)[i] = r;
  }
}

// ---------------- GEMM: C = A * Bm^T (+bias). 128x128 tile, BK=32 ----------------
template <int EPI>
__global__ __launch_bounds__(256)
void gemm_bt(const unsigned short* __restrict__ A, const unsigned short* __restrict__ Bm,
             int K,
             const float* __restrict__ bias0, const float* __restrict__ bias1,
             const float* __restrict__ bias2,
             unsigned short* __restrict__ qkv_out, float* __restrict__ f_out) {
  __shared__ short As[128][40];
  __shared__ short Bs[128][40];
  const int n0 = blockIdx.x * 128;
  const int m0 = blockIdx.y * 128;
  const int t = threadIdx.x;
  const int lane = t & 63;
  const int w = t >> 6, wm = w >> 1, wn = w & 1;
  const int sr = t >> 2, sc = (t & 3) * 8;
  const unsigned short* ga = A + (m0 + sr) * K + sc;
  const unsigned short* gb = Bm + (n0 + sr) * K + sc;
  f32x4 acc[4][4] = {};
  for (int kt = 0; kt < K; kt += 32) {
    short8 a0 = *(const short8*)(ga + kt);
    short8 a1 = *(const short8*)(ga + kt + 64 * K);
    short8 b0 = *(const short8*)(gb + kt);
    short8 b1 = *(const short8*)(gb + kt + 64 * K);
    __syncthreads();
    *(short8*)&As[sr][sc] = a0;
    *(short8*)&As[sr + 64][sc] = a1;
    *(short8*)&Bs[sr][sc] = b0;
    *(short8*)&Bs[sr + 64][sc] = b1;
    __syncthreads();
    short8 af[4], bfr[4];
#pragma unroll
    for (int i = 0; i < 4; i++) {
      af[i]  = *(const short8*)&As[wm * 64 + i * 16 + (lane & 15)][(lane >> 4) * 8];
      bfr[i] = *(const short8*)&Bs[wn * 64 + i * 16 + (lane & 15)][(lane >> 4) * 8];
    }
#pragma unroll
    for (int mi = 0; mi < 4; mi++)
#pragma unroll
      for (int ni = 0; ni < 4; ni++)
        acc[mi][ni] = mfma_bf16(af[mi], bfr[ni], acc[mi][ni]);
  }
  if constexpr (EPI == 0) {
    const int tix = n0 / 768;
    const float* bias = (tix == 0) ? bias0 : (tix == 1) ? bias1 : bias2;
    const float qs = (tix == 0) ? QSCALE : 1.0f;   // pre-scale Q into log2 domain
    unsigned short* dst = qkv_out + tix * (2 * NHEAD * S_LEN * 64);
#pragma unroll
    for (int mi = 0; mi < 4; mi++) {
      const int r0 = m0 + wm * 64 + mi * 16 + ((lane >> 4) << 2);
#pragma unroll
      for (int ni = 0; ni < 4; ni++) {
        const int jr = (n0 - tix * 768) + wn * 64 + ni * 16 + (lane & 15);
        const int h = jr >> 6, d = jr & 63;
        const float bv = bias[jr];
#pragma unroll
        for (int reg = 0; reg < 4; reg++) {
          const int r = r0 + reg;
          const int b = r >> 12, s = r & (S_LEN - 1);
          dst[(((b * NHEAD + h) * S_LEN + s) << 6) + d] = f2bf((acc[mi][ni][reg] + bv) * qs);
        }
      }
    }
  } else {
#pragma unroll
    for (int mi = 0; mi < 4; mi++) {
      const int r0 = m0 + wm * 64 + mi * 16 + ((lane >> 4) << 2);
#pragma unroll
      for (int ni = 0; ni < 4; ni++) {
        const int gc = n0 + wn * 64 + ni * 16 + (lane & 15);
        const float bv = bias0[gc];
#pragma unroll
        for (int reg = 0; reg < 4; reg++)
          f_out[(r0 + reg) * 768 + gc] = acc[mi][ni][reg] + bv;
      }
    }
  }
}

// ---------------- flash attention (swapped QK^T, split-K in-block) ----------------
// grid (S/128, B*H), 512 thr = 8 waves. Waves 0-3: keys [0,2048); 4-7: [2048,4096).
// Each wave owns 32 q-rows (2 qi). Partials merged in LDS at the end.
// NOTE: __launch_bounds__ 2nd arg behaves as min WORKGROUPS/CU here (round-4
// post-mortem: (512,5) forced VGPR=48 -> full scratch spill, 1.8 GB traffic).
// (512,2): VGPR cap 128, natural alloc ~90 -> no spill, 16 waves/CU.
union ShMem {
  short kv[2][2][64][72];   // [z][K=0/V=1][row][col(+pad)]  = 36864 B
  float mg[9216];           // merge: o[256][32] (XOR-swz) + ml[256][4] at 8192
};

__global__ __launch_bounds__(512, 2)
void attn_kernel(const unsigned short* __restrict__ Q, const unsigned short* __restrict__ Km,
                 const unsigned short* __restrict__ V, const int* __restrict__ mask,
                 unsigned short* __restrict__ ctx) {
  __shared__ ShMem sh;
  const int qt = blockIdx.x;
  const int bh = blockIdx.y;
  const int b = bh / NHEAD, h = bh % NHEAD;
  const unsigned short* Qb = Q + bh * (S_LEN * 64);
  const unsigned short* Kb = Km + bh * (S_LEN * 64);
  const unsigned short* Vb = V + bh * (S_LEN * 64);
  const int* mb = mask + b * S_LEN;
  const int t = threadIdx.x, lane = t & 63, w = t >> 6;
  const int z = w >> 2, wq = w & 3, tz = t & 255;
  const int c = lane & 15, g = lane >> 4;
  const int q0 = qt * 128 + wq * 32;
  const int kbase = z * 2048;
  short (*Ks)[72] = sh.kv[z][0];
  short (*Vt)[72] = sh.kv[z][1];

  // Q as QKT/PV B-operand: qf[qi][kk] = Q[q0+qi*16+c][kk*32+g*8 ..+8] (pre-scaled)
  short8 qf[2][2];
#pragma unroll
  for (int qi = 0; qi < 2; qi++)
#pragma unroll
    for (int kk = 0; kk < 2; kk++)
      qf[qi][kk] = *(const short8*)(Qb + (q0 + qi * 16 + c) * 64 + kk * 32 + g * 8);

  f32x4 oacc[4][2] = {};          // O^T frag: [dmi][qi], reg r -> d=16dmi+4g+r, q=16qi+c
  float mrun[2], lrun[2];
  mrun[0] = mrun[1] = -__builtin_inff();
  lrun[0] = lrun[1] = 0.f;

  const int sr = tz >> 3, sc = (tz & 7) * 8;   // staging within z-group: full 64x64
  const int swzw = (tz & 7) << 3;              // Vt write swizzle ((d>>3)<<3)
  const int idx_a = c + 32 * (g & 1);          // bpermute sources for PV B-frag
  const int idx_b = idx_a + 16;
  const bool hi_sel = (lane >= 32);

  for (int k0 = kbase; k0 < kbase + 2048; k0 += 64) {
    short8 kv0 = *(const short8*)(Kb + (k0 + sr) * 64 + sc);
    short8 kv1 = *(const short8*)(Kb + (k0 + sr + 32) * 64 + sc);
    short8 vv0 = *(const short8*)(Vb + (k0 + sr) * 64 + sc);
    short8 vv1 = *(const short8*)(Vb + (k0 + sr + 32) * 64 + sc);
    __syncthreads();
    *(short8*)&Ks[sr][sc] = kv0;
    *(short8*)&Ks[sr + 32][sc] = kv1;
#pragma unroll
    for (int j = 0; j < 8; j++) {
      Vt[sc + j][sr ^ swzw] = vv0[j];
      Vt[sc + j][(sr + 32) ^ swzw] = vv1[j];
    }
    __syncthreads();

    // S^T = K Q^T (already in log2 domain via Q pre-scale)
    f32x4 st[2][4];
    __builtin_amdgcn_s_setprio(1);
#pragma unroll
    for (int mi = 0; mi < 4; mi++) {
      short8 ka0 = *(const short8*)&Ks[mi * 16 + c][g * 8];
      short8 ka1 = *(const short8*)&Ks[mi * 16 + c][32 + g * 8];
#pragma unroll
      for (int qi = 0; qi < 2; qi++) {
        f32x4 zz = {0.f, 0.f, 0.f, 0.f};
        zz = mfma_bf16(ka0, qf[qi][0], zz);
        zz = mfma_bf16(ka1, qf[qi][1], zz);
        st[qi][mi] = zz;
      }
    }
    __builtin_amdgcn_s_setprio(0);
    // additive mask bias (per-key, amortized over qi); key = k0+16mi+4g+r
    f32x4 maskb[4];
#pragma unroll
    for (int mi = 0; mi < 4; mi++) {
      i32x4 mk = *(const i32x4*)(mb + k0 + 16 * mi + 4 * g);
#pragma unroll
      for (int r = 0; r < 4; r++) maskb[mi][r] = (mk[r] == 0) ? NEGB2 : 0.f;
    }
#pragma unroll
    for (int qi = 0; qi < 2; qi++)
#pragma unroll
      for (int mi = 0; mi < 4; mi++)
#pragma unroll
        for (int r = 0; r < 4; r++) st[qi][mi][r] += maskb[mi][r];
    // row max (in-register + cross-group shfl)
    float pm[2];
#pragma unroll
    for (int qi = 0; qi < 2; qi++) {
      float x = st[qi][0][0];
#pragma unroll
      for (int mi = 0; mi < 4; mi++)
#pragma unroll
        for (int r = 0; r < 4; r++) x = fmaxf(x, st[qi][mi][r]);
      x = fmaxf(x, __shfl_xor(x, 16));
      x = fmaxf(x, __shfl_xor(x, 32));
      pm[qi] = x;
    }
    // defer-max (T13): rescale only when max grew past THR2 (wave-uniform branch)
    if (!__all((pm[0] <= mrun[0] + THR2) && (pm[1] <= mrun[1] + THR2))) {
#pragma unroll
      for (int qi = 0; qi < 2; qi++) {
        float mnew = fmaxf(mrun[qi], pm[qi]);
        float al = __builtin_amdgcn_exp2f(mrun[qi] - mnew);
        mrun[qi] = mnew;
        lrun[qi] *= al;
#pragma unroll
        for (int dmi = 0; dmi < 4; dmi++)
#pragma unroll
          for (int r = 0; r < 4; r++) oacc[dmi][qi][r] *= al;
      }
    }
    // P = exp2(st - m), row-sum
#pragma unroll
    for (int qi = 0; qi < 2; qi++) {
      float ps = 0.f;
#pragma unroll
      for (int mi = 0; mi < 4; mi++)
#pragma unroll
        for (int r = 0; r < 4; r++) {
          float p = __builtin_amdgcn_exp2f(st[qi][mi][r] - mrun[qi]);
          st[qi][mi][r] = p;
          ps += p;
        }
      ps += __shfl_xor(ps, 16);
      ps += __shfl_xor(ps, 32);
      lrun[qi] += ps;
    }
    // pack P to bf16 pairs
    unsigned uu[2][4][2];
#pragma unroll
    for (int qi = 0; qi < 2; qi++)
#pragma unroll
      for (int mi = 0; mi < 4; mi++) {
        asm("v_cvt_pk_bf16_f32 %0, %1, %2"
            : "=v"(uu[qi][mi][0]) : "v"(st[qi][mi][0]), "v"(st[qi][mi][1]));
        asm("v_cvt_pk_bf16_f32 %0, %1, %2"
            : "=v"(uu[qi][mi][1]) : "v"(st[qi][mi][2]), "v"(st[qi][mi][3]));
      }
    // PV: O^T += Vt . P^T
#pragma unroll
    for (int kk = 0; kk < 2; kk++) {
      short8 pb[2];
#pragma unroll
      for (int qi = 0; qi < 2; qi++) {
        int a0 = __shfl((int)uu[qi][2 * kk][0], idx_a);
        int b0 = __shfl((int)uu[qi][2 * kk + 1][0], idx_a);
        int a1 = __shfl((int)uu[qi][2 * kk][1], idx_a);
        int b1 = __shfl((int)uu[qi][2 * kk + 1][1], idx_a);
        int a2 = __shfl((int)uu[qi][2 * kk][0], idx_b);
        int b2 = __shfl((int)uu[qi][2 * kk + 1][0], idx_b);
        int a3 = __shfl((int)uu[qi][2 * kk][1], idx_b);
        int b3 = __shfl((int)uu[qi][2 * kk + 1][1], idx_b);
        i32x4 dw;
        dw[0] = hi_sel ? b0 : a0;
        dw[1] = hi_sel ? b1 : a1;
        dw[2] = hi_sel ? b2 : a2;
        dw[3] = hi_sel ? b3 : a3;
        pb[qi] = __builtin_bit_cast(short8, dw);
      }
      __builtin_amdgcn_s_setprio(1);
#pragma unroll
      for (int dmi = 0; dmi < 4; dmi++) {
        const int hsw = ((2 * dmi + (c >> 3)) & 7) << 3;
        short8 vf = *(const short8*)&Vt[16 * dmi + c][(32 * kk + 8 * g) ^ hsw];
        oacc[dmi][0] = mfma_bf16(vf, pb[0], oacc[dmi][0]);
        oacc[dmi][1] = mfma_bf16(vf, pb[1], oacc[dmi][1]);
      }
      __builtin_amdgcn_s_setprio(0);
    }
  }

  // -------- in-LDS merge of the two K-halves --------
  __syncthreads();   // all tiles done; kv region free for reuse
  if (z == 1) {
#pragma unroll
    for (int dmi = 0; dmi < 4; dmi++)
#pragma unroll
      for (int qi = 0; qi < 2; qi++)
        *(f32x4*)&sh.mg[tz * 32 + ((dmi * 2 + qi) ^ (tz & 7)) * 4] = oacc[dmi][qi];
    f32x4 mlv = {mrun[0], mrun[1], lrun[0], lrun[1]};
    *(f32x4*)&sh.mg[8192 + tz * 4] = mlv;
  }
  __syncthreads();
  if (z == 0) {
    f32x4 ml1 = *(const f32x4*)&sh.mg[8192 + tz * 4];
    float a0s[2], a1s[2], inv[2];
#pragma unroll
    for (int qi = 0; qi < 2; qi++) {
      float m1 = ml1[qi], l1 = ml1[2 + qi];
      float mm = fmaxf(mrun[qi], m1);
      a0s[qi] = __builtin_amdgcn_exp2f(mrun[qi] - mm);
      a1s[qi] = __builtin_amdgcn_exp2f(m1 - mm);
      inv[qi] = 1.0f / (lrun[qi] * a0s[qi] + l1 * a1s[qi]);
    }
#pragma unroll
    for (int qi = 0; qi < 2; qi++) {
      const int row = q0 + qi * 16 + c;
#pragma unroll
      for (int dmi = 0; dmi < 4; dmi++) {
        f32x4 o1 = *(const f32x4*)&sh.mg[tz * 32 + ((dmi * 2 + qi) ^ (tz & 7)) * 4];
        float x0 = (oacc[dmi][qi][0] * a0s[qi] + o1[0] * a1s[qi]) * inv[qi];
        float x1 = (oacc[dmi][qi][1] * a0s[qi] + o1[1] * a1s[qi]) * inv[qi];
        float x2 = (oacc[dmi][qi][2] * a0s[qi] + o1[2] * a1s[qi]) * inv[qi];
        float x3 = (oacc[dmi][qi][3] * a0s[qi] + o1[3] * a1s[qi]) * inv[qi];
        unsigned p0, p1;
        asm("v_cvt_pk_bf16_f32 %0, %1, %2" : "=v"(p0) : "v"(x0), "v"(x1));
        asm("v_cvt_pk_bf16_f32 %0, %1, %2" : "=v"(p1) : "v"(x2), "v"(x3));
        uint2 u2v; u2v.x = p0; u2v.y = p1;
        *(uint2*)&ctx[(size_t)(b * S_LEN + row) * 768 + h * 64 + 16 * dmi + 4 * g] = u2v;
      }
    }
  }
}

// ---------------- launch ----------------
extern "C" void kernel_launch(void* const* d_in, const int* in_sizes, int n_in,
                              void* d_out, int out_size, void* d_ws, size_t ws_size,
                              hipStream_t stream) {
  const float* x  = (const float*)d_in[0];
  const int* mask = (const int*)d_in[1];
  const float* Wq = (const float*)d_in[2];
  const float* bq = (const float*)d_in[3];
  const float* Wk = (const float*)d_in[4];
  const float* bk = (const float*)d_in[5];
  const float* Wv = (const float*)d_in[6];
  const float* bv = (const float*)d_in[7];
  const float* Wo = (const float*)d_in[8];
  const float* bo = (const float*)d_in[9];
  float* out = (float*)d_out;

  const int NE = 8192 * 768;
  const int WE = 768 * 768;
  unsigned short* ws   = (unsigned short*)d_ws;
  unsigned short* xb   = ws;               // x bf16 [8192][768]
  unsigned short* wqkv = xb + NE;          // [2304][768]
  unsigned short* wob  = wqkv + 3 * WE;    // [768][768]
  unsigned short* qb   = wob + WE;         // Q|K|V each [24][4096][64]
  unsigned short* ctxb = qb + 3 * NE;      // ctx bf16 [8192][768]

  cvt_kernel<<<dim3(2048), 256, 0, stream>>>(x, xb, NE / 8);
  cvt_kernel<<<dim3(288), 256, 0, stream>>>(Wq, wqkv, WE / 8);
  cvt_kernel<<<dim3(288), 256, 0, stream>>>(Wk, wqkv + WE, WE / 8);
  cvt_kernel<<<dim3(288), 256, 0, stream>>>(Wv, wqkv + 2 * WE, WE / 8);
  cvt_kernel<<<dim3(288), 256, 0, stream>>>(Wo, wob, WE / 8);

  gemm_bt<0><<<dim3(18, 64), 256, 0, stream>>>(xb, wqkv, 768, bq, bk, bv, qb, nullptr);
  attn_kernel<<<dim3(32, 24), 512, 0, stream>>>(qb, qb + NE, qb + 2 * NE, mask, ctxb);
  gemm_bt<1><<<dim3(6, 64), 256, 0, stream>>>(ctxb, wob, 768, bo, nullptr, nullptr,
                                              nullptr, out);
}

// Round 6
// 393.621 us; speedup vs baseline: 2.1047x; 1.0904x over previous
//
#include <hip/hip_runtime.h>

// MHA forward: B=2, S=4096, H=12, HD=64, D=768. f32 in/out, bf16 MFMA compute.
// Pipeline: cvt(x,W)->bf16 | GEMM qkv (Q pre-scaled by 0.125*log2e) -> Q,K,V
//           | flash attn (4 waves, dbuf K/V, swizzled LDS, P-through-LDS,
//             exp2 softmax, defer-max) -> ctx bf16 | GEMM out -> f32.

#define S_LEN 4096
#define NHEAD 12
#define NEGB2 (-1.442695e9f)   // -1e9 * log2(e): mask bias in log2 domain
#define THR2 11.541561f        // defer-max threshold: 8 nats in log2
#define QSCALE 0.18033688f     // 0.125 * log2(e)

typedef __attribute__((ext_vector_type(8))) short short8;
typedef __attribute__((ext_vector_type(4))) float f32x4;
typedef __attribute__((ext_vector_type(4))) int i32x4;

__device__ __forceinline__ unsigned short f2bf(float f) {
  unsigned u = __builtin_bit_cast(unsigned, f);
  u += 0x7fffu + ((u >> 16) & 1u);   // round-to-nearest-even
  return (unsigned short)(u >> 16);
}

__device__ __forceinline__ f32x4 mfma_bf16(short8 a, short8 b, f32x4 c) {
  return __builtin_amdgcn_mfma_f32_16x16x32_bf16(a, b, c, 0, 0, 0);
}

// ---------------- f32 -> bf16 convert, 8 elems/thread ----------------
__global__ __launch_bounds__(256) void cvt_kernel(const float* __restrict__ in,
                                                  unsigned short* __restrict__ out,
                                                  int n8) {
  int i = blockIdx.x * blockDim.x + threadIdx.x;
  int stride = gridDim.x * blockDim.x;
  for (; i < n8; i += stride) {
    float4 a = ((const float4*)in)[i * 2];
    float4 b = ((const float4*)in)[i * 2 + 1];
    short8 r;
    r[0] = (short)f2bf(a.x); r[1] = (short)f2bf(a.y);
    r[2] = (short)f2bf(a.z); r[3] = (short)f2bf(a.w);
    r[4] = (short)f2bf(b.x); r[5] = (short)f2bf(b.y);
    r[6] = (short)f2bf(b.z); r[7] = (short)f2bf(b.w);
    ((short8*)out)[i] = r;
  }
}

// ---------------- GEMM: C = A * Bm^T (+bias). 128x128 tile, BK=32 ----------------
template <int EPI>
__global__ __launch_bounds__(256)
void gemm_bt(const unsigned short* __restrict__ A, const unsigned short* __restrict__ Bm,
             int K,
             const float* __restrict__ bias0, const float* __restrict__ bias1,
             const float* __restrict__ bias2,
             unsigned short* __restrict__ qkv_out, float* __restrict__ f_out) {
  __shared__ short As[128][40];
  __shared__ short Bs[128][40];
  const int n0 = blockIdx.x * 128;
  const int m0 = blockIdx.y * 128;
  const int t = threadIdx.x;
  const int lane = t & 63;
  const int w = t >> 6, wm = w >> 1, wn = w & 1;
  const int sr = t >> 2, sc = (t & 3) * 8;
  const unsigned short* ga = A + (m0 + sr) * K + sc;
  const unsigned short* gb = Bm + (n0 + sr) * K + sc;
  f32x4 acc[4][4] = {};
  for (int kt = 0; kt < K; kt += 32) {
    short8 a0 = *(const short8*)(ga + kt);
    short8 a1 = *(const short8*)(ga + kt + 64 * K);
    short8 b0 = *(const short8*)(gb + kt);
    short8 b1 = *(const short8*)(gb + kt + 64 * K);
    __syncthreads();
    *(short8*)&As[sr][sc] = a0;
    *(short8*)&As[sr + 64][sc] = a1;
    *(short8*)&Bs[sr][sc] = b0;
    *(short8*)&Bs[sr + 64][sc] = b1;
    __syncthreads();
    short8 af[4], bfr[4];
#pragma unroll
    for (int i = 0; i < 4; i++) {
      af[i]  = *(const short8*)&As[wm * 64 + i * 16 + (lane & 15)][(lane >> 4) * 8];
      bfr[i] = *(const short8*)&Bs[wn * 64 + i * 16 + (lane & 15)][(lane >> 4) * 8];
    }
#pragma unroll
    for (int mi = 0; mi < 4; mi++)
#pragma unroll
      for (int ni = 0; ni < 4; ni++)
        acc[mi][ni] = mfma_bf16(af[mi], bfr[ni], acc[mi][ni]);
  }
  if constexpr (EPI == 0) {
    const int tix = n0 / 768;
    const float* bias = (tix == 0) ? bias0 : (tix == 1) ? bias1 : bias2;
    const float qs = (tix == 0) ? QSCALE : 1.0f;   // pre-scale Q into log2 domain
    unsigned short* dst = qkv_out + tix * (2 * NHEAD * S_LEN * 64);
#pragma unroll
    for (int mi = 0; mi < 4; mi++) {
      const int r0 = m0 + wm * 64 + mi * 16 + ((lane >> 4) << 2);
#pragma unroll
      for (int ni = 0; ni < 4; ni++) {
        const int jr = (n0 - tix * 768) + wn * 64 + ni * 16 + (lane & 15);
        const int h = jr >> 6, d = jr & 63;
        const float bv = bias[jr];
#pragma unroll
        for (int reg = 0; reg < 4; reg++) {
          const int r = r0 + reg;
          const int b = r >> 12, s = r & (S_LEN - 1);
          dst[(((b * NHEAD + h) * S_LEN + s) << 6) + d] = f2bf((acc[mi][ni][reg] + bv) * qs);
        }
      }
    }
  } else {
#pragma unroll
    for (int mi = 0; mi < 4; mi++) {
      const int r0 = m0 + wm * 64 + mi * 16 + ((lane >> 4) << 2);
#pragma unroll
      for (int ni = 0; ni < 4; ni++) {
        const int gc = n0 + wn * 64 + ni * 16 + (lane & 15);
        const float bv = bias0[gc];
#pragma unroll
        for (int reg = 0; reg < 4; reg++)
          f_out[(r0 + reg) * 768 + gc] = acc[mi][ni][reg] + bv;
      }
    }
  }
}

// ---------------- flash attention ----------------
// grid (S/128, B*H), 256 thr = 4 waves; wave owns 32 q-rows. KV tile 64, dbuf.
// S^T = mfma(K,Q) (log2 domain); in-register softmax; P via wave-private LDS;
// O^T = mfma(V^T, P^T). Ks chunk-XOR swizzled; Vt [64][72] + key-XOR (as R3).
__global__ __launch_bounds__(256)
void attn_kernel(const unsigned short* __restrict__ Q, const unsigned short* __restrict__ Km,
                 const unsigned short* __restrict__ V, const int* __restrict__ mask,
                 unsigned short* __restrict__ ctx) {
  __shared__ short Ks[2][64][64];   // [buf][key][d-chunk^(key&7) swizzled]
  __shared__ short Vt[2][64][72];   // [buf][d][key ^ ((d>>3)<<3)]
  __shared__ short Ps[4][32][72];   // [wave][q][key] P^T staging (wave-private)
  const int qt = blockIdx.x;
  const int bh = blockIdx.y;
  const int b = bh / NHEAD, h = bh % NHEAD;
  const unsigned short* Qb = Q + bh * (S_LEN * 64);
  const unsigned short* Kb = Km + bh * (S_LEN * 64);
  const unsigned short* Vb = V + bh * (S_LEN * 64);
  const int* mb = mask + b * S_LEN;
  const int t = threadIdx.x, lane = t & 63, w = t >> 6;
  const int c = lane & 15, g = lane >> 4;
  const int q0 = qt * 128 + w * 32;

  // Q as QKT B-operand: qf[qi][kk] = Q[q0+qi*16+c][kk*32+g*8 ..+8] (pre-scaled)
  short8 qf[2][2];
#pragma unroll
  for (int qi = 0; qi < 2; qi++)
#pragma unroll
    for (int kk = 0; kk < 2; kk++)
      qf[qi][kk] = *(const short8*)(Qb + (q0 + qi * 16 + c) * 64 + kk * 32 + g * 8);

  f32x4 oacc[4][2] = {};          // O^T frag: [dmi][qi], reg r -> d=16dmi+4g+r, q=16qi+c
  float mrun[2], lrun[2];
  mrun[0] = mrun[1] = -__builtin_inff();
  lrun[0] = lrun[1] = 0.f;

  const int sr = t >> 3, k8 = t & 7, sc = k8 * 8;  // staging: key row, d-chunk
  const int swzw = k8 << 3;                        // Vt write swizzle ((d>>3)<<3)
  const int kx = (k8 ^ (sr & 7)) * 8;              // Ks chunk-XOR write col

  // prologue: stage tile 0 into buf 0
  {
    short8 kv0 = *(const short8*)(Kb + sr * 64 + sc);
    short8 kv1 = *(const short8*)(Kb + (sr + 32) * 64 + sc);
    short8 vv0 = *(const short8*)(Vb + sr * 64 + sc);
    short8 vv1 = *(const short8*)(Vb + (sr + 32) * 64 + sc);
    *(short8*)&Ks[0][sr][kx] = kv0;
    *(short8*)&Ks[0][sr + 32][kx] = kv1;
#pragma unroll
    for (int j = 0; j < 8; j++) {
      Vt[0][sc + j][sr ^ swzw] = vv0[j];
      Vt[0][sc + j][(sr + 32) ^ swzw] = vv1[j];
    }
  }
  __syncthreads();

  for (int it = 0; it < 64; ++it) {
    const int bd = it & 1;
    const int k0 = it * 64;
    // prefetch next tile into regs (HBM latency hides under compute)
    short8 nk0, nk1, nv0, nv1;
    if (it < 63) {
      const int kn = k0 + 64;
      nk0 = *(const short8*)(Kb + (kn + sr) * 64 + sc);
      nk1 = *(const short8*)(Kb + (kn + sr + 32) * 64 + sc);
      nv0 = *(const short8*)(Vb + (kn + sr) * 64 + sc);
      nv1 = *(const short8*)(Vb + (kn + sr + 32) * 64 + sc);
    }

    // S^T = K Q^T : A = Ks rows (key), chunk-XOR read
    f32x4 st[2][4];
    __builtin_amdgcn_s_setprio(1);
#pragma unroll
    for (int mi = 0; mi < 4; mi++) {
      short8 ka0 = *(const short8*)&Ks[bd][mi * 16 + c][(g ^ (c & 7)) * 8];
      short8 ka1 = *(const short8*)&Ks[bd][mi * 16 + c][((4 + g) ^ (c & 7)) * 8];
#pragma unroll
      for (int qi = 0; qi < 2; qi++) {
        f32x4 zz = {0.f, 0.f, 0.f, 0.f};
        zz = mfma_bf16(ka0, qf[qi][0], zz);
        zz = mfma_bf16(ka1, qf[qi][1], zz);
        st[qi][mi] = zz;
      }
    }
    __builtin_amdgcn_s_setprio(0);
    // additive mask bias; key = k0+16mi+4g+r
    f32x4 maskb[4];
#pragma unroll
    for (int mi = 0; mi < 4; mi++) {
      i32x4 mk = *(const i32x4*)(mb + k0 + 16 * mi + 4 * g);
#pragma unroll
      for (int r = 0; r < 4; r++) maskb[mi][r] = (mk[r] == 0) ? NEGB2 : 0.f;
    }
#pragma unroll
    for (int qi = 0; qi < 2; qi++)
#pragma unroll
      for (int mi = 0; mi < 4; mi++)
#pragma unroll
        for (int r = 0; r < 4; r++) st[qi][mi][r] += maskb[mi][r];
    // row max
    float pm[2];
#pragma unroll
    for (int qi = 0; qi < 2; qi++) {
      float x = st[qi][0][0];
#pragma unroll
      for (int mi = 0; mi < 4; mi++)
#pragma unroll
        for (int r = 0; r < 4; r++) x = fmaxf(x, st[qi][mi][r]);
      x = fmaxf(x, __shfl_xor(x, 16));
      x = fmaxf(x, __shfl_xor(x, 32));
      pm[qi] = x;
    }
    // defer-max (T13)
    if (!__all((pm[0] <= mrun[0] + THR2) && (pm[1] <= mrun[1] + THR2))) {
#pragma unroll
      for (int qi = 0; qi < 2; qi++) {
        float mnew = fmaxf(mrun[qi], pm[qi]);
        float al = __builtin_amdgcn_exp2f(mrun[qi] - mnew);
        mrun[qi] = mnew;
        lrun[qi] *= al;
#pragma unroll
        for (int dmi = 0; dmi < 4; dmi++)
#pragma unroll
          for (int r = 0; r < 4; r++) oacc[dmi][qi][r] *= al;
      }
    }
    // P = exp2(st - m), row-sum, pack to bf16, stage to wave-private LDS
#pragma unroll
    for (int qi = 0; qi < 2; qi++) {
      float ps = 0.f;
#pragma unroll
      for (int mi = 0; mi < 4; mi++)
#pragma unroll
        for (int r = 0; r < 4; r++) {
          float p = __builtin_amdgcn_exp2f(st[qi][mi][r] - mrun[qi]);
          st[qi][mi][r] = p;
          ps += p;
        }
      ps += __shfl_xor(ps, 16);
      ps += __shfl_xor(ps, 32);
      lrun[qi] += ps;
    }
#pragma unroll
    for (int qi = 0; qi < 2; qi++)
#pragma unroll
      for (int mi = 0; mi < 4; mi++) {
        unsigned u0, u1;
        asm("v_cvt_pk_bf16_f32 %0, %1, %2"
            : "=v"(u0) : "v"(st[qi][mi][0]), "v"(st[qi][mi][1]));
        asm("v_cvt_pk_bf16_f32 %0, %1, %2"
            : "=v"(u1) : "v"(st[qi][mi][2]), "v"(st[qi][mi][3]));
        uint2 uv; uv.x = u0; uv.y = u1;
        *(uint2*)&Ps[w][16 * qi + c][16 * mi + 4 * g] = uv;  // keys 16mi+4g..+3
      }
    // PV: O^T += Vt . P^T ; B-frag = Ps row read (b128), A-frag = Vt rows
#pragma unroll
    for (int kk = 0; kk < 2; kk++) {
      short8 pb[2];
#pragma unroll
      for (int qi = 0; qi < 2; qi++)
        pb[qi] = *(const short8*)&Ps[w][16 * qi + c][32 * kk + 8 * g];
      __builtin_amdgcn_s_setprio(1);
#pragma unroll
      for (int dmi = 0; dmi < 4; dmi++) {
        const int hsw = ((2 * dmi + (c >> 3)) & 7) << 3;
        short8 vf = *(const short8*)&Vt[bd][16 * dmi + c][(32 * kk + 8 * g) ^ hsw];
        oacc[dmi][0] = mfma_bf16(vf, pb[0], oacc[dmi][0]);
        oacc[dmi][1] = mfma_bf16(vf, pb[1], oacc[dmi][1]);
      }
      __builtin_amdgcn_s_setprio(0);
    }
    // stage next tile into other buffer, then single barrier
    if (it < 63) {
      *(short8*)&Ks[bd ^ 1][sr][kx] = nk0;
      *(short8*)&Ks[bd ^ 1][sr + 32][kx] = nk1;
#pragma unroll
      for (int j = 0; j < 8; j++) {
        Vt[bd ^ 1][sc + j][sr ^ swzw] = nv0[j];
        Vt[bd ^ 1][sc + j][(sr + 32) ^ swzw] = nv1[j];
      }
    }
    __syncthreads();
  }
  // epilogue: O^T -> ctx[b][q][h*64+d]
#pragma unroll
  for (int qi = 0; qi < 2; qi++) {
    const float inv = 1.f / lrun[qi];
    const int row = q0 + qi * 16 + c;
#pragma unroll
    for (int dmi = 0; dmi < 4; dmi++) {
      float x0 = oacc[dmi][qi][0] * inv, x1 = oacc[dmi][qi][1] * inv;
      float x2 = oacc[dmi][qi][2] * inv, x3 = oacc[dmi][qi][3] * inv;
      unsigned p0, p1;
      asm("v_cvt_pk_bf16_f32 %0, %1, %2" : "=v"(p0) : "v"(x0), "v"(x1));
      asm("v_cvt_pk_bf16_f32 %0, %1, %2" : "=v"(p1) : "v"(x2), "v"(x3));
      uint2 u2v; u2v.x = p0; u2v.y = p1;
      *(uint2*)&ctx[(size_t)(b * S_LEN + row) * 768 + h * 64 + 16 * dmi + 4 * g] = u2v;
    }
  }
}

// ---------------- launch ----------------
extern "C" void kernel_launch(void* const* d_in, const int* in_sizes, int n_in,
                              void* d_out, int out_size, void* d_ws, size_t ws_size,
                              hipStream_t stream) {
  const float* x  = (const float*)d_in[0];
  const int* mask = (const int*)d_in[1];
  const float* Wq = (const float*)d_in[2];
  const float* bq = (const float*)d_in[3];
  const float* Wk = (const float*)d_in[4];
  const float* bk = (const float*)d_in[5];
  const float* Wv = (const float*)d_in[6];
  const float* bv = (const float*)d_in[7];
  const float* Wo = (const float*)d_in[8];
  const float* bo = (const float*)d_in[9];
  float* out = (float*)d_out;

  const int NE = 8192 * 768;
  const int WE = 768 * 768;
  unsigned short* ws   = (unsigned short*)d_ws;
  unsigned short* xb   = ws;               // x bf16 [8192][768]
  unsigned short* wqkv = xb + NE;          // [2304][768]
  unsigned short* wob  = wqkv + 3 * WE;    // [768][768]
  unsigned short* qb   = wob + WE;         // Q|K|V each [24][4096][64]
  unsigned short* ctxb = qb + 3 * NE;      // ctx bf16 [8192][768]

  cvt_kernel<<<dim3(2048), 256, 0, stream>>>(x, xb, NE / 8);
  cvt_kernel<<<dim3(288), 256, 0, stream>>>(Wq, wqkv, WE / 8);
  cvt_kernel<<<dim3(288), 256, 0, stream>>>(Wk, wqkv + WE, WE / 8);
  cvt_kernel<<<dim3(288), 256, 0, stream>>>(Wv, wqkv + 2 * WE, WE / 8);
  cvt_kernel<<<dim3(288), 256, 0, stream>>>(Wo, wob, WE / 8);

  gemm_bt<0><<<dim3(18, 64), 256, 0, stream>>>(xb, wqkv, 768, bq, bk, bv, qb, nullptr);
  attn_kernel<<<dim3(32, 24), 256, 0, stream>>>(qb, qb + NE, qb + 2 * NE, mask, ctxb);
  gemm_bt<1><<<dim3(6, 64), 256, 0, stream>>>(ctxb, wob, 768, bo, nullptr, nullptr,
                                              nullptr, out);
}

// Round 8
// 300.084 us; speedup vs baseline: 2.7607x; 1.3117x over previous
//
#include <hip/hip_runtime.h>

// MHA forward: B=2, S=4096, H=12, HD=64, D=768. f32 in/out, bf16 MFMA compute.
// Key algorithmic trick: mask==0 keys contribute EXACTLY 0 (exp(-1e9-m)
// underflows in f32) -> compact K/V to unmasked keys (~50%) and attend over
// cnt[b] keys only. Pipeline: mask_scan | cvt -> bf16 | GEMM qkv (Q pre-scaled
// 0.125*log2e; K/V scattered to compact slots) | flash attn (dbuf, swizzled
// LDS, exp2 softmax, defer-max) | GEMM out -> f32.

#define S_LEN 4096
#define NHEAD 12
#define NEGB2 (-1.442695e9f)   // -1e9 * log2(e): pad bias in log2 domain
#define THR2 11.541561f        // defer-max threshold: 8 nats in log2
#define QSCALE 0.18033688f     // 0.125 * log2(e)

typedef __attribute__((ext_vector_type(8))) short short8;
typedef __attribute__((ext_vector_type(4))) float f32x4;
typedef __attribute__((ext_vector_type(4))) int i32x4;

__device__ __forceinline__ unsigned short f2bf(float f) {
  unsigned u = __builtin_bit_cast(unsigned, f);
  u += 0x7fffu + ((u >> 16) & 1u);   // round-to-nearest-even
  return (unsigned short)(u >> 16);
}

__device__ __forceinline__ f32x4 mfma_bf16(short8 a, short8 b, f32x4 c) {
  return __builtin_amdgcn_mfma_f32_16x16x32_bf16(a, b, c, 0, 0, 0);
}

// ---------------- mask scan: pos[b][s] = compact slot or -1; cnt[b] ----------------
__global__ __launch_bounds__(64) void mask_scan(const int* __restrict__ mask,
                                                int* __restrict__ pos,
                                                int* __restrict__ cnt) {
  const int b = blockIdx.x;
  const int lane = threadIdx.x;       // one wave per batch
  const int* mb = mask + b * S_LEN;
  int* pb = pos + b * S_LEN;
  const int base = lane * 64;
  int cntl = 0;
  for (int j = 0; j < 64; j++) cntl += (mb[base + j] != 0);
  int x = cntl;                        // inclusive wave prefix
#pragma unroll
  for (int off = 1; off < 64; off <<= 1) {
    int y = __shfl_up(x, off);
    if (lane >= off) x += y;
  }
  const int total = __shfl(x, 63);
  int o = x - cntl;                    // exclusive prefix
  for (int j = 0; j < 64; j++) {
    const int mv = mb[base + j];
    pb[base + j] = (mv != 0) ? o : -1;
    o += (mv != 0);
  }
  if (lane == 0) cnt[b] = total;
}

// ---------------- f32 -> bf16 convert, 8 elems/thread ----------------
__global__ __launch_bounds__(256) void cvt_kernel(const float* __restrict__ in,
                                                  unsigned short* __restrict__ out,
                                                  int n8) {
  int i = blockIdx.x * blockDim.x + threadIdx.x;
  int stride = gridDim.x * blockDim.x;
  for (; i < n8; i += stride) {
    float4 a = ((const float4*)in)[i * 2];
    float4 b = ((const float4*)in)[i * 2 + 1];
    short8 r;
    r[0] = (short)f2bf(a.x); r[1] = (short)f2bf(a.y);
    r[2] = (short)f2bf(a.z); r[3] = (short)f2bf(a.w);
    r[4] = (short)f2bf(b.x); r[5] = (short)f2bf(b.y);
    r[6] = (short)f2bf(b.z); r[7] = (short)f2bf(b.w);
    ((short8*)out)[i] = r;
  }
}

// 4 weight matrices (wqkv|wob contiguous in dst) in one launch
__global__ __launch_bounds__(256) void cvt_w4_kernel(const float* __restrict__ w0,
                                                     const float* __restrict__ w1,
                                                     const float* __restrict__ w2,
                                                     const float* __restrict__ w3,
                                                     unsigned short* __restrict__ out,
                                                     int n8) {
  const int k = blockIdx.y;
  const float* in = (k == 0) ? w0 : (k == 1) ? w1 : (k == 2) ? w2 : w3;
  unsigned short* dst = out + (size_t)k * n8 * 8;
  int i = blockIdx.x * blockDim.x + threadIdx.x;
  int stride = gridDim.x * blockDim.x;
  for (; i < n8; i += stride) {
    float4 a = ((const float4*)in)[i * 2];
    float4 b = ((const float4*)in)[i * 2 + 1];
    short8 r;
    r[0] = (short)f2bf(a.x); r[1] = (short)f2bf(a.y);
    r[2] = (short)f2bf(a.z); r[3] = (short)f2bf(a.w);
    r[4] = (short)f2bf(b.x); r[5] = (short)f2bf(b.y);
    r[6] = (short)f2bf(b.z); r[7] = (short)f2bf(b.w);
    ((short8*)dst)[i] = r;
  }
}

// ---------------- GEMM: C = A * Bm^T (+bias). 128x128 tile, BK=32 ----------------
// EPI=0: tix0 -> Q [B,H,S,64] (scaled); tix1/2 -> K/V compacted via pos[].
// EPI=1: f32 out + bias.
template <int EPI>
__global__ __launch_bounds__(256)
void gemm_bt(const unsigned short* __restrict__ A, const unsigned short* __restrict__ Bm,
             int K,
             const float* __restrict__ bias0, const float* __restrict__ bias1,
             const float* __restrict__ bias2, const int* __restrict__ pos,
             unsigned short* __restrict__ qkv_out, float* __restrict__ f_out) {
  __shared__ short As[128][40];
  __shared__ short Bs[128][40];
  const int n0 = blockIdx.x * 128;
  const int m0 = blockIdx.y * 128;
  const int t = threadIdx.x;
  const int lane = t & 63;
  const int w = t >> 6, wm = w >> 1, wn = w & 1;
  const int sr = t >> 2, sc = (t & 3) * 8;
  const unsigned short* ga = A + (m0 + sr) * K + sc;
  const unsigned short* gb = Bm + (n0 + sr) * K + sc;
  f32x4 acc[4][4] = {};
  for (int kt = 0; kt < K; kt += 32) {
    short8 a0 = *(const short8*)(ga + kt);
    short8 a1 = *(const short8*)(ga + kt + 64 * K);
    short8 b0 = *(const short8*)(gb + kt);
    short8 b1 = *(const short8*)(gb + kt + 64 * K);
    __syncthreads();
    *(short8*)&As[sr][sc] = a0;
    *(short8*)&As[sr + 64][sc] = a1;
    *(short8*)&Bs[sr][sc] = b0;
    *(short8*)&Bs[sr + 64][sc] = b1;
    __syncthreads();
    short8 af[4], bfr[4];
#pragma unroll
    for (int i = 0; i < 4; i++) {
      af[i]  = *(const short8*)&As[wm * 64 + i * 16 + (lane & 15)][(lane >> 4) * 8];
      bfr[i] = *(const short8*)&Bs[wn * 64 + i * 16 + (lane & 15)][(lane >> 4) * 8];
    }
#pragma unroll
    for (int mi = 0; mi < 4; mi++)
#pragma unroll
      for (int ni = 0; ni < 4; ni++)
        acc[mi][ni] = mfma_bf16(af[mi], bfr[ni], acc[mi][ni]);
  }
  if constexpr (EPI == 0) {
    const int tix = n0 / 768;   // 0=q 1=k 2=v (uniform per block)
    const float* bias = (tix == 0) ? bias0 : (tix == 1) ? bias1 : bias2;
    unsigned short* dst = qkv_out + tix * (2 * NHEAD * S_LEN * 64);
    if (tix == 0) {
#pragma unroll
      for (int mi = 0; mi < 4; mi++) {
        const int r0 = m0 + wm * 64 + mi * 16 + ((lane >> 4) << 2);
#pragma unroll
        for (int ni = 0; ni < 4; ni++) {
          const int jr = n0 + wn * 64 + ni * 16 + (lane & 15);
          const int h = jr >> 6, d = jr & 63;
          const float bv = bias[jr];
#pragma unroll
          for (int reg = 0; reg < 4; reg++) {
            const int r = r0 + reg;
            const int b = r >> 12, s = r & (S_LEN - 1);
            dst[(((b * NHEAD + h) * S_LEN + s) << 6) + d] =
                f2bf((acc[mi][ni][reg] + bv) * QSCALE);
          }
        }
      }
    } else {
      // K/V: scatter rows to compact slots; drop masked rows
#pragma unroll
      for (int mi = 0; mi < 4; mi++) {
        const int r0 = m0 + wm * 64 + mi * 16 + ((lane >> 4) << 2);
#pragma unroll
        for (int reg = 0; reg < 4; reg++) {
          const int r = r0 + reg;
          const int b = r >> 12, s = r & (S_LEN - 1);
          const int cpos = pos[b * S_LEN + s];
          if (cpos >= 0) {
#pragma unroll
            for (int ni = 0; ni < 4; ni++) {
              const int jr = (n0 - tix * 768) + wn * 64 + ni * 16 + (lane & 15);
              const int h = jr >> 6, d = jr & 63;
              dst[(((b * NHEAD + h) * S_LEN + cpos) << 6) + d] =
                  f2bf(acc[mi][ni][reg] + bias[jr]);
            }
          }
        }
      }
    }
  } else {
#pragma unroll
    for (int mi = 0; mi < 4; mi++) {
      const int r0 = m0 + wm * 64 + mi * 16 + ((lane >> 4) << 2);
#pragma unroll
      for (int ni = 0; ni < 4; ni++) {
        const int gc = n0 + wn * 64 + ni * 16 + (lane & 15);
        const float bv = bias0[gc];
#pragma unroll
        for (int reg = 0; reg < 4; reg++)
          f_out[(r0 + reg) * 768 + gc] = acc[mi][ni][reg] + bv;
      }
    }
  }
}

// ---------------- flash attention over compacted keys ----------------
// grid (S/128, B*H), 256 thr = 4 waves; wave owns 32 q-rows. KV tile 64, dbuf.
// S^T = mfma(K,Q) (log2 domain); in-register softmax; P via wave-private LDS;
// O^T = mfma(V^T, P^T). Only the last partial tile needs a pad bias.
__global__ __launch_bounds__(256)
void attn_kernel(const unsigned short* __restrict__ Q, const unsigned short* __restrict__ Km,
                 const unsigned short* __restrict__ V, const int* __restrict__ cnt,
                 unsigned short* __restrict__ ctx) {
  __shared__ short Ks[2][64][64];   // [buf][key][d-chunk^(key&7) swizzled]
  __shared__ short Vt[2][64][72];   // [buf][d][key ^ ((d>>3)<<3)]
  __shared__ short Ps[4][32][72];   // [wave][q][key] P^T staging (wave-private)
  const int qt = blockIdx.x;
  const int bh = blockIdx.y;
  const int b = bh / NHEAD, h = bh % NHEAD;
  const unsigned short* Qb = Q + bh * (S_LEN * 64);
  const unsigned short* Kb = Km + bh * (S_LEN * 64);
  const unsigned short* Vb = V + bh * (S_LEN * 64);
  const int t = threadIdx.x, lane = t & 63, w = t >> 6;
  const int c = lane & 15, g = lane >> 4;
  const int q0 = qt * 128 + w * 32;
  const int cntb = cnt[b];
  const int ntiles = (cntb + 63) >> 6;

  // Q as QKT B-operand: qf[qi][kk] = Q[q0+qi*16+c][kk*32+g*8 ..+8] (pre-scaled)
  short8 qf[2][2];
#pragma unroll
  for (int qi = 0; qi < 2; qi++)
#pragma unroll
    for (int kk = 0; kk < 2; kk++)
      qf[qi][kk] = *(const short8*)(Qb + (q0 + qi * 16 + c) * 64 + kk * 32 + g * 8);

  f32x4 oacc[4][2] = {};          // O^T frag: [dmi][qi], reg r -> d=16dmi+4g+r, q=16qi+c
  float mrun[2], lrun[2];
  mrun[0] = mrun[1] = -__builtin_inff();
  lrun[0] = lrun[1] = 0.f;

  const int sr = t >> 3, k8 = t & 7, sc = k8 * 8;  // staging: key row, d-chunk
  const int swzw = k8 << 3;                        // Vt write swizzle ((d>>3)<<3)
  const int kx = (k8 ^ (sr & 7)) * 8;              // Ks chunk-XOR write col

  // prologue: stage tile 0 into buf 0
  {
    short8 kv0 = *(const short8*)(Kb + sr * 64 + sc);
    short8 kv1 = *(const short8*)(Kb + (sr + 32) * 64 + sc);
    short8 vv0 = *(const short8*)(Vb + sr * 64 + sc);
    short8 vv1 = *(const short8*)(Vb + (sr + 32) * 64 + sc);
    *(short8*)&Ks[0][sr][kx] = kv0;
    *(short8*)&Ks[0][sr + 32][kx] = kv1;
#pragma unroll
    for (int j = 0; j < 8; j++) {
      Vt[0][sc + j][sr ^ swzw] = vv0[j];
      Vt[0][sc + j][(sr + 32) ^ swzw] = vv1[j];
    }
  }
  __syncthreads();

  for (int it = 0; it < ntiles; ++it) {
    const int bd = it & 1;
    const int k0 = it * 64;
    // prefetch next tile into regs (HBM latency hides under compute)
    short8 nk0, nk1, nv0, nv1;
    if (it < ntiles - 1) {
      const int kn = k0 + 64;
      nk0 = *(const short8*)(Kb + (kn + sr) * 64 + sc);
      nk1 = *(const short8*)(Kb + (kn + sr + 32) * 64 + sc);
      nv0 = *(const short8*)(Vb + (kn + sr) * 64 + sc);
      nv1 = *(const short8*)(Vb + (kn + sr + 32) * 64 + sc);
    }

    // S^T = K Q^T : A = Ks rows (key), chunk-XOR read
    f32x4 st[2][4];
    __builtin_amdgcn_s_setprio(1);
#pragma unroll
    for (int mi = 0; mi < 4; mi++) {
      short8 ka0 = *(const short8*)&Ks[bd][mi * 16 + c][(g ^ (c & 7)) * 8];
      short8 ka1 = *(const short8*)&Ks[bd][mi * 16 + c][((4 + g) ^ (c & 7)) * 8];
#pragma unroll
      for (int qi = 0; qi < 2; qi++) {
        f32x4 zz = {0.f, 0.f, 0.f, 0.f};
        zz = mfma_bf16(ka0, qf[qi][0], zz);
        zz = mfma_bf16(ka1, qf[qi][1], zz);
        st[qi][mi] = zz;
      }
    }
    __builtin_amdgcn_s_setprio(0);
    // pad bias only on the last partial tile; slot = k0+16mi+4g+r
    if (k0 + 64 > cntb) {
#pragma unroll
      for (int mi = 0; mi < 4; mi++)
#pragma unroll
        for (int r = 0; r < 4; r++) {
          const float pb = (k0 + 16 * mi + 4 * g + r >= cntb) ? NEGB2 : 0.f;
          st[0][mi][r] += pb;
          st[1][mi][r] += pb;
        }
    }
    // row max
    float pm[2];
#pragma unroll
    for (int qi = 0; qi < 2; qi++) {
      float x = st[qi][0][0];
#pragma unroll
      for (int mi = 0; mi < 4; mi++)
#pragma unroll
        for (int r = 0; r < 4; r++) x = fmaxf(x, st[qi][mi][r]);
      x = fmaxf(x, __shfl_xor(x, 16));
      x = fmaxf(x, __shfl_xor(x, 32));
      pm[qi] = x;
    }
    // defer-max (T13)
    if (!__all((pm[0] <= mrun[0] + THR2) && (pm[1] <= mrun[1] + THR2))) {
#pragma unroll
      for (int qi = 0; qi < 2; qi++) {
        float mnew = fmaxf(mrun[qi], pm[qi]);
        float al = __builtin_amdgcn_exp2f(mrun[qi] - mnew);
        mrun[qi] = mnew;
        lrun[qi] *= al;
#pragma unroll
        for (int dmi = 0; dmi < 4; dmi++)
#pragma unroll
          for (int r = 0; r < 4; r++) oacc[dmi][qi][r] *= al;
      }
    }
    // P = exp2(st - m), row-sum, pack to bf16, stage to wave-private LDS
#pragma unroll
    for (int qi = 0; qi < 2; qi++) {
      float ps = 0.f;
#pragma unroll
      for (int mi = 0; mi < 4; mi++)
#pragma unroll
        for (int r = 0; r < 4; r++) {
          float p = __builtin_amdgcn_exp2f(st[qi][mi][r] - mrun[qi]);
          st[qi][mi][r] = p;
          ps += p;
        }
      ps += __shfl_xor(ps, 16);
      ps += __shfl_xor(ps, 32);
      lrun[qi] += ps;
    }
#pragma unroll
    for (int qi = 0; qi < 2; qi++)
#pragma unroll
      for (int mi = 0; mi < 4; mi++) {
        unsigned u0, u1;
        asm("v_cvt_pk_bf16_f32 %0, %1, %2"
            : "=v"(u0) : "v"(st[qi][mi][0]), "v"(st[qi][mi][1]));
        asm("v_cvt_pk_bf16_f32 %0, %1, %2"
            : "=v"(u1) : "v"(st[qi][mi][2]), "v"(st[qi][mi][3]));
        uint2 uv; uv.x = u0; uv.y = u1;
        *(uint2*)&Ps[w][16 * qi + c][16 * mi + 4 * g] = uv;  // keys 16mi+4g..+3
      }
    // PV: O^T += Vt . P^T ; B-frag = Ps row read (b128), A-frag = Vt rows
#pragma unroll
    for (int kk = 0; kk < 2; kk++) {
      short8 pb[2];
#pragma unroll
      for (int qi = 0; qi < 2; qi++)
        pb[qi] = *(const short8*)&Ps[w][16 * qi + c][32 * kk + 8 * g];
      __builtin_amdgcn_s_setprio(1);
#pragma unroll
      for (int dmi = 0; dmi < 4; dmi++) {
        const int hsw = ((2 * dmi + (c >> 3)) & 7) << 3;
        short8 vf = *(const short8*)&Vt[bd][16 * dmi + c][(32 * kk + 8 * g) ^ hsw];
        oacc[dmi][0] = mfma_bf16(vf, pb[0], oacc[dmi][0]);
        oacc[dmi][1] = mfma_bf16(vf, pb[1], oacc[dmi][1]);
      }
      __builtin_amdgcn_s_setprio(0);
    }
    // stage next tile into other buffer, then single barrier
    if (it < ntiles - 1) {
      *(short8*)&Ks[bd ^ 1][sr][kx] = nk0;
      *(short8*)&Ks[bd ^ 1][sr + 32][kx] = nk1;
#pragma unroll
      for (int j = 0; j < 8; j++) {
        Vt[bd ^ 1][sc + j][sr ^ swzw] = nv0[j];
        Vt[bd ^ 1][sc + j][(sr + 32) ^ swzw] = nv1[j];
      }
    }
    __syncthreads();
  }
  // epilogue: O^T -> ctx[b][q][h*64+d]
#pragma unroll
  for (int qi = 0; qi < 2; qi++) {
    const float inv = 1.f / lrun[qi];
    const int row = q0 + qi * 16 + c;
#pragma unroll
    for (int dmi = 0; dmi < 4; dmi++) {
      float x0 = oacc[dmi][qi][0] * inv, x1 = oacc[dmi][qi][1] * inv;
      float x2 = oacc[dmi][qi][2] * inv, x3 = oacc[dmi][qi][3] * inv;
      unsigned p0, p1;
      asm("v_cvt_pk_bf16_f32 %0, %1, %2" : "=v"(p0) : "v"(x0), "v"(x1));
      asm("v_cvt_pk_bf16_f32 %0, %1, %2" : "=v"(p1) : "v"(x2), "v"(x3));
      uint2 u2v; u2v.x = p0; u2v.y = p1;
      *(uint2*)&ctx[(size_t)(b * S_LEN + row) * 768 + h * 64 + 16 * dmi + 4 * g] = u2v;
    }
  }
}

// ---------------- launch ----------------
extern "C" void kernel_launch(void* const* d_in, const int* in_sizes, int n_in,
                              void* d_out, int out_size, void* d_ws, size_t ws_size,
                              hipStream_t stream) {
  const float* x  = (const float*)d_in[0];
  const int* mask = (const int*)d_in[1];
  const float* Wq = (const float*)d_in[2];
  const float* bq = (const float*)d_in[3];
  const float* Wk = (const float*)d_in[4];
  const float* bk = (const float*)d_in[5];
  const float* Wv = (const float*)d_in[6];
  const float* bv = (const float*)d_in[7];
  const float* Wo = (const float*)d_in[8];
  const float* bo = (const float*)d_in[9];
  float* out = (float*)d_out;

  const int NE = 8192 * 768;
  const int WE = 768 * 768;
  unsigned short* ws   = (unsigned short*)d_ws;
  unsigned short* xb   = ws;               // x bf16 [8192][768]
  unsigned short* wqkv = xb + NE;          // [2304][768]
  unsigned short* wob  = wqkv + 3 * WE;    // [768][768] (contiguous after wqkv)
  unsigned short* qb   = wob + WE;         // Q | Kc | Vc each [24][4096][64]
  unsigned short* ctxb = qb + 3 * NE;      // ctx bf16 [8192][768]
  int* pos = (int*)(ctxb + NE);            // [2][4096]
  int* cnt = pos + 2 * S_LEN;              // [2]

  mask_scan<<<dim3(2), 64, 0, stream>>>(mask, pos, cnt);
  cvt_kernel<<<dim3(2048), 256, 0, stream>>>(x, xb, NE / 8);
  cvt_w4_kernel<<<dim3(288, 4), 256, 0, stream>>>(Wq, Wk, Wv, Wo, wqkv, WE / 8);

  gemm_bt<0><<<dim3(18, 64), 256, 0, stream>>>(xb, wqkv, 768, bq, bk, bv, pos,
                                               qb, nullptr);
  attn_kernel<<<dim3(32, 24), 256, 0, stream>>>(qb, qb + NE, qb + 2 * NE, cnt, ctxb);
  gemm_bt<1><<<dim3(6, 64), 256, 0, stream>>>(ctxb, wob, 768, bo, nullptr, nullptr,
                                              nullptr, nullptr, out);
}

// Round 9
// 299.132 us; speedup vs baseline: 2.7695x; 1.0032x over previous
//
#include <hip/hip_runtime.h>

// MHA forward: B=2, S=4096, H=12, HD=64, D=768. f32 in/out, bf16 MFMA compute.
// mask==0 keys contribute exactly 0 -> compact K/V (~50%). V stored TRANSPOSED
// [BH][64][4096]. Staging via global_load_lds (linear dest, pre-swizzled
// source, XOR-swizzled reads). P redistribution via permlane swaps (VALU pipe,
// not LDS). GEMMs: m97-style gload_lds + dbuf + single barrier/K-step.

#define S_LEN 4096
#define NHEAD 12
#define NEGB2 (-1.442695e9f)   // -1e9 * log2(e): pad bias in log2 domain
#define THR2 11.541561f        // defer-max threshold: 8 nats in log2
#define QSCALE 0.18033688f     // 0.125 * log2(e)

typedef __attribute__((ext_vector_type(8))) short short8;
typedef __attribute__((ext_vector_type(4))) float f32x4;
typedef __attribute__((ext_vector_type(4))) int i32x4;

__device__ __forceinline__ unsigned short f2bf(float f) {
  unsigned u = __builtin_bit_cast(unsigned, f);
  u += 0x7fffu + ((u >> 16) & 1u);   // round-to-nearest-even
  return (unsigned short)(u >> 16);
}

__device__ __forceinline__ f32x4 mfma_bf16(short8 a, short8 b, f32x4 c) {
  return __builtin_amdgcn_mfma_f32_16x16x32_bf16(a, b, c, 0, 0, 0);
}

// async global->LDS, 16B/lane; lds ptr must be the WAVE base (HW adds lane*16)
__device__ __forceinline__ void gload16(const void* g, void* l) {
  __builtin_amdgcn_global_load_lds(
      (const __attribute__((address_space(1))) void*)g,
      (__attribute__((address_space(3))) void*)l, 16, 0, 0);
}

// ---------------- mask scan: pos[b][s] = compact slot or -1; cnt[b] ----------------
__global__ __launch_bounds__(64) void mask_scan(const int* __restrict__ mask,
                                                int* __restrict__ pos,
                                                int* __restrict__ cnt) {
  const int b = blockIdx.x;
  const int lane = threadIdx.x;       // one wave per batch
  const int* mb = mask + b * S_LEN;
  int* pb = pos + b * S_LEN;
  const int base = lane * 64;
  int cntl = 0;
  for (int j = 0; j < 64; j++) cntl += (mb[base + j] != 0);
  int x = cntl;                        // inclusive wave prefix
#pragma unroll
  for (int off = 1; off < 64; off <<= 1) {
    int y = __shfl_up(x, off);
    if (lane >= off) x += y;
  }
  const int total = __shfl(x, 63);
  int o = x - cntl;                    // exclusive prefix
  for (int j = 0; j < 64; j++) {
    const int mv = mb[base + j];
    pb[base + j] = (mv != 0) ? o : -1;
    o += (mv != 0);
  }
  if (lane == 0) cnt[b] = total;
}

// ---------------- f32 -> bf16 convert, 8 elems/thread ----------------
__global__ __launch_bounds__(256) void cvt_kernel(const float* __restrict__ in,
                                                  unsigned short* __restrict__ out,
                                                  int n8) {
  int i = blockIdx.x * blockDim.x + threadIdx.x;
  int stride = gridDim.x * blockDim.x;
  for (; i < n8; i += stride) {
    float4 a = ((const float4*)in)[i * 2];
    float4 b = ((const float4*)in)[i * 2 + 1];
    short8 r;
    r[0] = (short)f2bf(a.x); r[1] = (short)f2bf(a.y);
    r[2] = (short)f2bf(a.z); r[3] = (short)f2bf(a.w);
    r[4] = (short)f2bf(b.x); r[5] = (short)f2bf(b.y);
    r[6] = (short)f2bf(b.z); r[7] = (short)f2bf(b.w);
    ((short8*)out)[i] = r;
  }
}

// 4 weight matrices (wqkv|wob contiguous in dst) in one launch
__global__ __launch_bounds__(256) void cvt_w4_kernel(const float* __restrict__ w0,
                                                     const float* __restrict__ w1,
                                                     const float* __restrict__ w2,
                                                     const float* __restrict__ w3,
                                                     unsigned short* __restrict__ out,
                                                     int n8) {
  const int k = blockIdx.y;
  const float* in = (k == 0) ? w0 : (k == 1) ? w1 : (k == 2) ? w2 : w3;
  unsigned short* dst = out + (size_t)k * n8 * 8;
  int i = blockIdx.x * blockDim.x + threadIdx.x;
  int stride = gridDim.x * blockDim.x;
  for (; i < n8; i += stride) {
    float4 a = ((const float4*)in)[i * 2];
    float4 b = ((const float4*)in)[i * 2 + 1];
    short8 r;
    r[0] = (short)f2bf(a.x); r[1] = (short)f2bf(a.y);
    r[2] = (short)f2bf(a.z); r[3] = (short)f2bf(a.w);
    r[4] = (short)f2bf(b.x); r[5] = (short)f2bf(b.y);
    r[6] = (short)f2bf(b.z); r[7] = (short)f2bf(b.w);
    ((short8*)dst)[i] = r;
  }
}

// ---------------- GEMM: C = A * Bm^T (+bias). 128x128 tile, BK=32 ----------------
// gload_lds staging, dbuf, 1 barrier/K-step, T2-lite swizzle chunk^((row>>1)&3).
// EPI=0: tix0 -> Q (scaled); tix1 -> K compact [BH][4096][64]; tix2 -> V compact
// TRANSPOSED [BH][64][4096]. EPI=1: f32 out + bias.
template <int EPI>
__global__ __launch_bounds__(256)
void gemm_bt(const unsigned short* __restrict__ A, const unsigned short* __restrict__ Bm,
             int K,
             const float* __restrict__ bias0, const float* __restrict__ bias1,
             const float* __restrict__ bias2, const int* __restrict__ pos,
             unsigned short* __restrict__ qkv_out, float* __restrict__ f_out) {
  __shared__ short As[2][128][32];
  __shared__ short Bs[2][128][32];
  const int n0 = blockIdx.x * 128;
  const int m0 = blockIdx.y * 128;
  const int t = threadIdx.x;
  const int lane = t & 63;
  const int w = t >> 6, wm = w >> 1, wn = w & 1;
  const int c = lane & 15, g = lane >> 4;
  const int srow = t >> 2, sch = t & 3;   // staging: pass-local row, lds chunk

  f32x4 acc[4][4] = {};
  const int nk = K >> 5;

#define G_STAGE(bsel, kt)                                                     \
  {                                                                           \
    _Pragma("unroll") for (int p = 0; p < 2; p++) {                           \
      const int row = p * 64 + srow;                                          \
      const int gcol = (kt) + ((sch ^ ((row >> 1) & 3)) * 8);                 \
      gload16(A + (size_t)(m0 + row) * K + gcol,                              \
              (char*)&As[bsel][0][0] + p * 4096 + (t >> 6) * 1024);           \
      gload16(Bm + (size_t)(n0 + row) * K + gcol,                             \
              (char*)&Bs[bsel][0][0] + p * 4096 + (t >> 6) * 1024);           \
    }                                                                         \
  }

  G_STAGE(0, 0);
  for (int kt = 0; kt < nk; kt++) {
    const int cur = kt & 1;
    __syncthreads();                       // gload(cur) done; prev reads done
    if (kt + 1 < nk) G_STAGE(cur ^ 1, (kt + 1) << 5);
    const int sw = (c >> 1) & 3;
    short8 af[4], bfr[4];
#pragma unroll
    for (int i = 0; i < 4; i++) {
      af[i]  = *(const short8*)&As[cur][wm * 64 + i * 16 + c][(g ^ sw) * 8];
      bfr[i] = *(const short8*)&Bs[cur][wn * 64 + i * 16 + c][(g ^ sw) * 8];
    }
#pragma unroll
    for (int mi = 0; mi < 4; mi++)
#pragma unroll
      for (int ni = 0; ni < 4; ni++)
        acc[mi][ni] = mfma_bf16(af[mi], bfr[ni], acc[mi][ni]);
  }
#undef G_STAGE

  if constexpr (EPI == 0) {
    const int tix = n0 / 768;   // 0=q 1=k 2=v (uniform per block)
    const float* bias = (tix == 0) ? bias0 : (tix == 1) ? bias1 : bias2;
    unsigned short* dst = qkv_out + tix * (2 * NHEAD * S_LEN * 64);
    if (tix == 0) {
#pragma unroll
      for (int mi = 0; mi < 4; mi++) {
        const int r0 = m0 + wm * 64 + mi * 16 + (g << 2);
#pragma unroll
        for (int ni = 0; ni < 4; ni++) {
          const int jr = n0 + wn * 64 + ni * 16 + c;
          const int h = jr >> 6, d = jr & 63;
          const float bv = bias[jr];
#pragma unroll
          for (int reg = 0; reg < 4; reg++) {
            const int r = r0 + reg;
            const int b = r >> 12, s = r & (S_LEN - 1);
            dst[(((b * NHEAD + h) * S_LEN + s) << 6) + d] =
                f2bf((acc[mi][ni][reg] + bv) * QSCALE);
          }
        }
      }
    } else if (tix == 1) {
      // K: scatter rows to compact slots [BH][4096][64]
#pragma unroll
      for (int mi = 0; mi < 4; mi++) {
        const int r0 = m0 + wm * 64 + mi * 16 + (g << 2);
#pragma unroll
        for (int reg = 0; reg < 4; reg++) {
          const int r = r0 + reg;
          const int b = r >> 12, s = r & (S_LEN - 1);
          const int cpos = pos[b * S_LEN + s];
          if (cpos >= 0) {
#pragma unroll
            for (int ni = 0; ni < 4; ni++) {
              const int jr = (n0 - 768) + wn * 64 + ni * 16 + c;
              const int h = jr >> 6, d = jr & 63;
              dst[(((b * NHEAD + h) * S_LEN + cpos) << 6) + d] =
                  f2bf(acc[mi][ni][reg] + bias[jr]);
            }
          }
        }
      }
    } else {
      // V: scatter TRANSPOSED [BH][64][4096] (2-B writes merge in L2: each
      // block's cpos range is ~64 contiguous slots = 1-2 lines per d-row)
#pragma unroll
      for (int mi = 0; mi < 4; mi++) {
        const int r0 = m0 + wm * 64 + mi * 16 + (g << 2);
#pragma unroll
        for (int reg = 0; reg < 4; reg++) {
          const int r = r0 + reg;
          const int b = r >> 12, s = r & (S_LEN - 1);
          const int cpos = pos[b * S_LEN + s];
          if (cpos >= 0) {
#pragma unroll
            for (int ni = 0; ni < 4; ni++) {
              const int jr = (n0 - 1536) + wn * 64 + ni * 16 + c;
              const int h = jr >> 6, d = jr & 63;
              dst[((size_t)((b * NHEAD + h) * 64 + d) << 12) + cpos] =
                  f2bf(acc[mi][ni][reg] + bias[jr]);
            }
          }
        }
      }
    }
  } else {
#pragma unroll
    for (int mi = 0; mi < 4; mi++) {
      const int r0 = m0 + wm * 64 + mi * 16 + (g << 2);
#pragma unroll
      for (int ni = 0; ni < 4; ni++) {
        const int gc = n0 + wn * 64 + ni * 16 + c;
        const float bv = bias0[gc];
#pragma unroll
        for (int reg = 0; reg < 4; reg++)
          f_out[(r0 + reg) * 768 + gc] = acc[mi][ni][reg] + bv;
      }
    }
  }
}

// ---------------- flash attention over compacted keys ----------------
// grid (S/128, B*H), 256 thr = 4 waves; wave owns 32 q-rows. KV tile 64, dbuf.
// gload_lds staging (source pre-swizzled chunk^(row&7)); S^T = mfma(K,Q) in
// log2 domain; in-register softmax; P via permlane32/16_swap (VALU, no LDS);
// O^T = mfma(V^T, P^T) with V^T staged from the transposed global layout.
__global__ __launch_bounds__(256)
void attn_kernel(const unsigned short* __restrict__ Q, const unsigned short* __restrict__ Km,
                 const unsigned short* __restrict__ Vtg, const int* __restrict__ cnt,
                 unsigned short* __restrict__ ctx) {
  __shared__ short Ks[2][64][64];   // [buf][key][d-chunk ^ (key&7)]
  __shared__ short Vt[2][64][64];   // [buf][d][key-chunk ^ (d&7)]
  const int qt = blockIdx.x;
  const int bh = blockIdx.y;
  const int b = bh / NHEAD, h = bh % NHEAD;
  const unsigned short* Qb = Q + bh * (S_LEN * 64);
  const unsigned short* Kb = Km + bh * (S_LEN * 64);
  const unsigned short* Vb = Vtg + (size_t)bh * 64 * S_LEN;
  const int t = threadIdx.x, lane = t & 63, w = t >> 6;
  const int c = lane & 15, g = lane >> 4;
  const int q0 = qt * 128 + w * 32;
  const int cntb = cnt[b];
  const int ntiles = (cntb + 63) >> 6;
  const bool lo32 = (lane < 32);

  // Q as QKT B-operand: qf[qi][kk] = Q[q0+qi*16+c][kk*32+g*8 ..+8] (pre-scaled)
  short8 qf[2][2];
#pragma unroll
  for (int qi = 0; qi < 2; qi++)
#pragma unroll
    for (int kk = 0; kk < 2; kk++)
      qf[qi][kk] = *(const short8*)(Qb + (q0 + qi * 16 + c) * 64 + kk * 32 + g * 8);

  f32x4 oacc[4][2] = {};          // O^T frag: [dmi][qi], reg r -> d=16dmi+4g+r, q=16qi+c
  float mrun[2], lrun[2];
  mrun[0] = mrun[1] = -__builtin_inff();
  lrun[0] = lrun[1] = 0.f;

  const int srow = t >> 3, sch = t & 7;   // staging: pass-local row, lds chunk

#define A_STAGE(bsel, k0v)                                                    \
  {                                                                           \
    _Pragma("unroll") for (int p = 0; p < 2; p++) {                           \
      const int row = p * 32 + srow;                                          \
      const int gc8 = ((sch ^ (row & 7)) * 8);                                \
      gload16(Kb + (size_t)((k0v) + row) * 64 + gc8,                          \
              (char*)&Ks[bsel][0][0] + p * 4096 + (t >> 6) * 1024);           \
      gload16(Vb + (size_t)row * S_LEN + (k0v) + gc8,                         \
              (char*)&Vt[bsel][0][0] + p * 4096 + (t >> 6) * 1024);           \
    }                                                                         \
  }

  A_STAGE(0, 0);

  for (int it = 0; it < ntiles; ++it) {
    const int bd = it & 1;
    const int k0 = it * 64;
    __syncthreads();                 // staged(bd) complete; prev reads done
    if (it + 1 < ntiles) A_STAGE(bd ^ 1, k0 + 64);

    // S^T = K Q^T (log2 domain)
    f32x4 st[2][4];
    __builtin_amdgcn_s_setprio(1);
#pragma unroll
    for (int mi = 0; mi < 4; mi++) {
      short8 ka0 = *(const short8*)&Ks[bd][mi * 16 + c][(g ^ (c & 7)) * 8];
      short8 ka1 = *(const short8*)&Ks[bd][mi * 16 + c][((4 + g) ^ (c & 7)) * 8];
#pragma unroll
      for (int qi = 0; qi < 2; qi++) {
        f32x4 zz = {0.f, 0.f, 0.f, 0.f};
        zz = mfma_bf16(ka0, qf[qi][0], zz);
        zz = mfma_bf16(ka1, qf[qi][1], zz);
        st[qi][mi] = zz;
      }
    }
    __builtin_amdgcn_s_setprio(0);
    // pad bias only on the last partial tile; slot = k0+16mi+4g+r
    if (k0 + 64 > cntb) {
#pragma unroll
      for (int mi = 0; mi < 4; mi++)
#pragma unroll
        for (int r = 0; r < 4; r++) {
          const float pb = (k0 + 16 * mi + 4 * g + r >= cntb) ? NEGB2 : 0.f;
          st[0][mi][r] += pb;
          st[1][mi][r] += pb;
        }
    }
    // row max
    float pm[2];
#pragma unroll
    for (int qi = 0; qi < 2; qi++) {
      float x = st[qi][0][0];
#pragma unroll
      for (int mi = 0; mi < 4; mi++)
#pragma unroll
        for (int r = 0; r < 4; r++) x = fmaxf(x, st[qi][mi][r]);
      x = fmaxf(x, __shfl_xor(x, 16));
      x = fmaxf(x, __shfl_xor(x, 32));
      pm[qi] = x;
    }
    // defer-max (T13)
    if (!__all((pm[0] <= mrun[0] + THR2) && (pm[1] <= mrun[1] + THR2))) {
#pragma unroll
      for (int qi = 0; qi < 2; qi++) {
        float mnew = fmaxf(mrun[qi], pm[qi]);
        float al = __builtin_amdgcn_exp2f(mrun[qi] - mnew);
        mrun[qi] = mnew;
        lrun[qi] *= al;
#pragma unroll
        for (int dmi = 0; dmi < 4; dmi++)
#pragma unroll
          for (int r = 0; r < 4; r++) oacc[dmi][qi][r] *= al;
      }
    }
    // P = exp2(st - m), row-sum, pack to bf16 (in registers)
    unsigned uu[2][4][2];
#pragma unroll
    for (int qi = 0; qi < 2; qi++) {
      float ps = 0.f;
#pragma unroll
      for (int mi = 0; mi < 4; mi++)
#pragma unroll
        for (int r = 0; r < 4; r++) {
          float p = __builtin_amdgcn_exp2f(st[qi][mi][r] - mrun[qi]);
          st[qi][mi][r] = p;
          ps += p;
        }
      ps += __shfl_xor(ps, 16);
      ps += __shfl_xor(ps, 32);
      lrun[qi] += ps;
#pragma unroll
      for (int mi = 0; mi < 4; mi++) {
        asm("v_cvt_pk_bf16_f32 %0, %1, %2"
            : "=v"(uu[qi][mi][0]) : "v"(st[qi][mi][0]), "v"(st[qi][mi][1]));
        asm("v_cvt_pk_bf16_f32 %0, %1, %2"
            : "=v"(uu[qi][mi][1]) : "v"(st[qi][mi][2]), "v"(st[qi][mi][3]));
      }
    }
    // PV: O^T += Vt . P^T. B-frag built in VALU via permlane swaps:
    // rowperm(R): Y0 rows = (R0,R2,R0,R2), Y1 = (R1,R3,R1,R3); blend a/b
    // registers by lane<32 (mi = 2kk + (g>>1)). dw_t at lane(c,g) =
    // pack(P[32kk+8g+2t], P[32kk+8g+2t+1]) -- verified element-wise.
#pragma unroll
    for (int kk = 0; kk < 2; kk++) {
      short8 pb[2];
#pragma unroll
      for (int qi = 0; qi < 2; qi++) {
        i32x4 dw;
#pragma unroll
        for (int x = 0; x < 2; x++) {
          unsigned pa = uu[qi][2 * kk][x], qa = pa;
          asm("v_permlane32_swap_b32 %0, %1" : "+v"(pa), "+v"(qa));
          asm("v_permlane16_swap_b32 %0, %1" : "+v"(pa), "+v"(qa));
          unsigned pbr = uu[qi][2 * kk + 1][x], qbr = pbr;
          asm("v_permlane32_swap_b32 %0, %1" : "+v"(pbr), "+v"(qbr));
          asm("v_permlane16_swap_b32 %0, %1" : "+v"(pbr), "+v"(qbr));
          dw[x]     = (int)(lo32 ? pa : pbr);   // t = 0 (x=0), 1 (x=1)
          dw[2 + x] = (int)(lo32 ? qa : qbr);   // t = 2, 3
        }
        pb[qi] = __builtin_bit_cast(short8, dw);
      }
      __builtin_amdgcn_s_setprio(1);
#pragma unroll
      for (int dmi = 0; dmi < 4; dmi++) {
        short8 vf = *(const short8*)&Vt[bd][16 * dmi + c][((4 * kk + g) ^ (c & 7)) * 8];
        oacc[dmi][0] = mfma_bf16(vf, pb[0], oacc[dmi][0]);
        oacc[dmi][1] = mfma_bf16(vf, pb[1], oacc[dmi][1]);
      }
      __builtin_amdgcn_s_setprio(0);
    }
  }
#undef A_STAGE
  // epilogue: O^T -> ctx[b][q][h*64+d]
#pragma unroll
  for (int qi = 0; qi < 2; qi++) {
    const float inv = 1.f / lrun[qi];
    const int row = q0 + qi * 16 + c;
#pragma unroll
    for (int dmi = 0; dmi < 4; dmi++) {
      float x0 = oacc[dmi][qi][0] * inv, x1 = oacc[dmi][qi][1] * inv;
      float x2 = oacc[dmi][qi][2] * inv, x3 = oacc[dmi][qi][3] * inv;
      unsigned p0, p1;
      asm("v_cvt_pk_bf16_f32 %0, %1, %2" : "=v"(p0) : "v"(x0), "v"(x1));
      asm("v_cvt_pk_bf16_f32 %0, %1, %2" : "=v"(p1) : "v"(x2), "v"(x3));
      uint2 u2v; u2v.x = p0; u2v.y = p1;
      *(uint2*)&ctx[(size_t)(b * S_LEN + row) * 768 + h * 64 + 16 * dmi + 4 * g] = u2v;
    }
  }
}

// ---------------- launch ----------------
extern "C" void kernel_launch(void* const* d_in, const int* in_sizes, int n_in,
                              void* d_out, int out_size, void* d_ws, size_t ws_size,
                              hipStream_t stream) {
  const float* x  = (const float*)d_in[0];
  const int* mask = (const int*)d_in[1];
  const float* Wq = (const float*)d_in[2];
  const float* bq = (const float*)d_in[3];
  const float* Wk = (const float*)d_in[4];
  const float* bk = (const float*)d_in[5];
  const float* Wv = (const float*)d_in[6];
  const float* bv = (const float*)d_in[7];
  const float* Wo = (const float*)d_in[8];
  const float* bo = (const float*)d_in[9];
  float* out = (float*)d_out;

  const int NE = 8192 * 768;
  const int WE = 768 * 768;
  unsigned short* ws   = (unsigned short*)d_ws;
  unsigned short* xb   = ws;               // x bf16 [8192][768]
  unsigned short* wqkv = xb + NE;          // [2304][768]
  unsigned short* wob  = wqkv + 3 * WE;    // [768][768] (contiguous after wqkv)
  unsigned short* qb   = wob + WE;         // Q [BH][4096][64] | Kc same | Vc^T [BH][64][4096]
  unsigned short* ctxb = qb + 3 * NE;      // ctx bf16 [8192][768]
  int* pos = (int*)(ctxb + NE);            // [2][4096]
  int* cnt = pos + 2 * S_LEN;              // [2]

  mask_scan<<<dim3(2), 64, 0, stream>>>(mask, pos, cnt);
  cvt_kernel<<<dim3(2048), 256, 0, stream>>>(x, xb, NE / 8);
  cvt_w4_kernel<<<dim3(288, 4), 256, 0, stream>>>(Wq, Wk, Wv, Wo, wqkv, WE / 8);

  gemm_bt<0><<<dim3(18, 64), 256, 0, stream>>>(xb, wqkv, 768, bq, bk, bv, pos,
                                               qb, nullptr);
  attn_kernel<<<dim3(32, 24), 256, 0, stream>>>(qb, qb + NE, qb + 2 * NE, cnt, ctxb);
  gemm_bt<1><<<dim3(6, 64), 256, 0, stream>>>(ctxb, wob, 768, bo, nullptr, nullptr,
                                              nullptr, nullptr, out);
}

// Round 10
// 296.799 us; speedup vs baseline: 2.7913x; 1.0079x over previous
//
#include <hip/hip_runtime.h>

// MHA forward: B=2, S=4096, H=12, HD=64, D=768. f32 in/out, bf16 MFMA compute.
// mask==0 keys contribute exactly 0 -> compact K/V (~50%), both row-major
// [BH][4096][64] (coalesced epilogue scatter). Attn: K staged via
// global_load_lds (pre-swizzled source), V scalar-transposed into LDS
// (XOR-swizzled); S^T = mfma(K,Q) in log2 domain; in-register softmax with
// tree reductions; P redistribution via permlane swaps (VALU pipe).

#define S_LEN 4096
#define NHEAD 12
#define NEGB2 (-1.442695e9f)   // -1e9 * log2(e): pad bias in log2 domain
#define THR2 11.541561f        // defer-max threshold: 8 nats in log2
#define QSCALE 0.18033688f     // 0.125 * log2(e)

typedef __attribute__((ext_vector_type(8))) short short8;
typedef __attribute__((ext_vector_type(4))) float f32x4;
typedef __attribute__((ext_vector_type(4))) int i32x4;

__device__ __forceinline__ unsigned short f2bf(float f) {
  unsigned u = __builtin_bit_cast(unsigned, f);
  u += 0x7fffu + ((u >> 16) & 1u);   // round-to-nearest-even
  return (unsigned short)(u >> 16);
}

__device__ __forceinline__ f32x4 mfma_bf16(short8 a, short8 b, f32x4 c) {
  return __builtin_amdgcn_mfma_f32_16x16x32_bf16(a, b, c, 0, 0, 0);
}

// async global->LDS, 16B/lane; lds ptr must be the WAVE base (HW adds lane*16)
__device__ __forceinline__ void gload16(const void* g, void* l) {
  __builtin_amdgcn_global_load_lds(
      (const __attribute__((address_space(1))) void*)g,
      (__attribute__((address_space(3))) void*)l, 16, 0, 0);
}

// ---------------- mask scan: pos[b][s] = compact slot or -1; cnt[b] ----------------
__global__ __launch_bounds__(64) void mask_scan(const int* __restrict__ mask,
                                                int* __restrict__ pos,
                                                int* __restrict__ cnt) {
  const int b = blockIdx.x;
  const int lane = threadIdx.x;       // one wave per batch
  const int* mb = mask + b * S_LEN;
  int* pb = pos + b * S_LEN;
  const int base = lane * 64;
  int cntl = 0;
  for (int j = 0; j < 64; j++) cntl += (mb[base + j] != 0);
  int x = cntl;                        // inclusive wave prefix
#pragma unroll
  for (int off = 1; off < 64; off <<= 1) {
    int y = __shfl_up(x, off);
    if (lane >= off) x += y;
  }
  const int total = __shfl(x, 63);
  int o = x - cntl;                    // exclusive prefix
  for (int j = 0; j < 64; j++) {
    const int mv = mb[base + j];
    pb[base + j] = (mv != 0) ? o : -1;
    o += (mv != 0);
  }
  if (lane == 0) cnt[b] = total;
}

// ---------------- f32 -> bf16 convert, 8 elems/thread ----------------
__global__ __launch_bounds__(256) void cvt_kernel(const float* __restrict__ in,
                                                  unsigned short* __restrict__ out,
                                                  int n8) {
  int i = blockIdx.x * blockDim.x + threadIdx.x;
  int stride = gridDim.x * blockDim.x;
  for (; i < n8; i += stride) {
    float4 a = ((const float4*)in)[i * 2];
    float4 b = ((const float4*)in)[i * 2 + 1];
    short8 r;
    r[0] = (short)f2bf(a.x); r[1] = (short)f2bf(a.y);
    r[2] = (short)f2bf(a.z); r[3] = (short)f2bf(a.w);
    r[4] = (short)f2bf(b.x); r[5] = (short)f2bf(b.y);
    r[6] = (short)f2bf(b.z); r[7] = (short)f2bf(b.w);
    ((short8*)out)[i] = r;
  }
}

// 4 weight matrices (wqkv|wob contiguous in dst) in one launch
__global__ __launch_bounds__(256) void cvt_w4_kernel(const float* __restrict__ w0,
                                                     const float* __restrict__ w1,
                                                     const float* __restrict__ w2,
                                                     const float* __restrict__ w3,
                                                     unsigned short* __restrict__ out,
                                                     int n8) {
  const int k = blockIdx.y;
  const float* in = (k == 0) ? w0 : (k == 1) ? w1 : (k == 2) ? w2 : w3;
  unsigned short* dst = out + (size_t)k * n8 * 8;
  int i = blockIdx.x * blockDim.x + threadIdx.x;
  int stride = gridDim.x * blockDim.x;
  for (; i < n8; i += stride) {
    float4 a = ((const float4*)in)[i * 2];
    float4 b = ((const float4*)in)[i * 2 + 1];
    short8 r;
    r[0] = (short)f2bf(a.x); r[1] = (short)f2bf(a.y);
    r[2] = (short)f2bf(a.z); r[3] = (short)f2bf(a.w);
    r[4] = (short)f2bf(b.x); r[5] = (short)f2bf(b.y);
    r[6] = (short)f2bf(b.z); r[7] = (short)f2bf(b.w);
    ((short8*)dst)[i] = r;
  }
}

// ---------------- GEMM: C = A * Bm^T (+bias). 128x128 tile, BK=32 ----------------
// gload_lds staging, dbuf, 1 barrier/K-step, T2-lite swizzle chunk^((row>>1)&3).
// EPI=0: tix0 -> Q (scaled); tix1/2 -> K/V compact row-major [BH][4096][64].
// EPI=1: f32 out + bias.
template <int EPI>
__global__ __launch_bounds__(256)
void gemm_bt(const unsigned short* __restrict__ A, const unsigned short* __restrict__ Bm,
             int K,
             const float* __restrict__ bias0, const float* __restrict__ bias1,
             const float* __restrict__ bias2, const int* __restrict__ pos,
             unsigned short* __restrict__ qkv_out, float* __restrict__ f_out) {
  __shared__ short As[2][128][32];
  __shared__ short Bs[2][128][32];
  const int n0 = blockIdx.x * 128;
  const int m0 = blockIdx.y * 128;
  const int t = threadIdx.x;
  const int lane = t & 63;
  const int w = t >> 6, wm = w >> 1, wn = w & 1;
  const int c = lane & 15, g = lane >> 4;
  const int srow = t >> 2, sch = t & 3;   // staging: pass-local row, lds chunk

  f32x4 acc[4][4] = {};
  const int nk = K >> 5;

#define G_STAGE(bsel, kt)                                                     \
  {                                                                           \
    _Pragma("unroll") for (int p = 0; p < 2; p++) {                           \
      const int row = p * 64 + srow;                                          \
      const int gcol = (kt) + ((sch ^ ((row >> 1) & 3)) * 8);                 \
      gload16(A + (size_t)(m0 + row) * K + gcol,                              \
              (char*)&As[bsel][0][0] + p * 4096 + (t >> 6) * 1024);           \
      gload16(Bm + (size_t)(n0 + row) * K + gcol,                             \
              (char*)&Bs[bsel][0][0] + p * 4096 + (t >> 6) * 1024);           \
    }                                                                         \
  }

  G_STAGE(0, 0);
  for (int kt = 0; kt < nk; kt++) {
    const int cur = kt & 1;
    __syncthreads();                       // gload(cur) done; prev reads done
    if (kt + 1 < nk) G_STAGE(cur ^ 1, (kt + 1) << 5);
    const int sw = (c >> 1) & 3;
    short8 af[4], bfr[4];
#pragma unroll
    for (int i = 0; i < 4; i++) {
      af[i]  = *(const short8*)&As[cur][wm * 64 + i * 16 + c][(g ^ sw) * 8];
      bfr[i] = *(const short8*)&Bs[cur][wn * 64 + i * 16 + c][(g ^ sw) * 8];
    }
#pragma unroll
    for (int mi = 0; mi < 4; mi++)
#pragma unroll
      for (int ni = 0; ni < 4; ni++)
        acc[mi][ni] = mfma_bf16(af[mi], bfr[ni], acc[mi][ni]);
  }
#undef G_STAGE

  if constexpr (EPI == 0) {
    const int tix = n0 / 768;   // 0=q 1=k 2=v (uniform per block)
    const float* bias = (tix == 0) ? bias0 : (tix == 1) ? bias1 : bias2;
    unsigned short* dst = qkv_out + tix * (2 * NHEAD * S_LEN * 64);
    if (tix == 0) {
#pragma unroll
      for (int mi = 0; mi < 4; mi++) {
        const int r0 = m0 + wm * 64 + mi * 16 + (g << 2);
#pragma unroll
        for (int ni = 0; ni < 4; ni++) {
          const int jr = n0 + wn * 64 + ni * 16 + c;
          const int h = jr >> 6, d = jr & 63;
          const float bv = bias[jr];
#pragma unroll
          for (int reg = 0; reg < 4; reg++) {
            const int r = r0 + reg;
            const int b = r >> 12, s = r & (S_LEN - 1);
            dst[(((b * NHEAD + h) * S_LEN + s) << 6) + d] =
                f2bf((acc[mi][ni][reg] + bv) * QSCALE);
          }
        }
      }
    } else {
      // K/V: scatter rows to compact slots, row-major [BH][4096][64]
#pragma unroll
      for (int mi = 0; mi < 4; mi++) {
        const int r0 = m0 + wm * 64 + mi * 16 + (g << 2);
#pragma unroll
        for (int reg = 0; reg < 4; reg++) {
          const int r = r0 + reg;
          const int b = r >> 12, s = r & (S_LEN - 1);
          const int cpos = pos[b * S_LEN + s];
          if (cpos >= 0) {
#pragma unroll
            for (int ni = 0; ni < 4; ni++) {
              const int jr = (n0 - tix * 768) + wn * 64 + ni * 16 + c;
              const int h = jr >> 6, d = jr & 63;
              dst[(((b * NHEAD + h) * S_LEN + cpos) << 6) + d] =
                  f2bf(acc[mi][ni][reg] + bias[jr]);
            }
          }
        }
      }
    }
  } else {
#pragma unroll
    for (int mi = 0; mi < 4; mi++) {
      const int r0 = m0 + wm * 64 + mi * 16 + (g << 2);
#pragma unroll
      for (int ni = 0; ni < 4; ni++) {
        const int gc = n0 + wn * 64 + ni * 16 + c;
        const float bv = bias0[gc];
#pragma unroll
        for (int reg = 0; reg < 4; reg++)
          f_out[(r0 + reg) * 768 + gc] = acc[mi][ni][reg] + bv;
      }
    }
  }
}

// ---------------- flash attention over compacted keys ----------------
// grid (S/128, B*H), 256 thr = 4 waves; wave owns 32 q-rows. KV tile 64, dbuf.
// K via gload_lds (pre-swizzled source, chunk-XOR reads); V scalar-transposed
// into Vt (key-XOR swizzle). S^T = mfma(K,Q) log2 domain; tree-reduced
// in-register softmax; P via permlane swaps; O^T = mfma(Vt, P^T).
__global__ __launch_bounds__(256)
void attn_kernel(const unsigned short* __restrict__ Q, const unsigned short* __restrict__ Km,
                 const unsigned short* __restrict__ V, const int* __restrict__ cnt,
                 unsigned short* __restrict__ ctx) {
  __shared__ short Ks[2][64][64];   // [buf][key][d-chunk ^ (key&7)]
  __shared__ short Vt[2][64][72];   // [buf][d][key ^ ((d>>3)<<3)]
  const int qt = blockIdx.x;
  const int bh = blockIdx.y;
  const int b = bh / NHEAD, h = bh % NHEAD;
  const unsigned short* Qb = Q + bh * (S_LEN * 64);
  const unsigned short* Kb = Km + bh * (S_LEN * 64);
  const unsigned short* Vb = V + bh * (S_LEN * 64);
  const int t = threadIdx.x, lane = t & 63, w = t >> 6;
  const int c = lane & 15, g = lane >> 4;
  const int q0 = qt * 128 + w * 32;
  const int cntb = cnt[b];
  const int ntiles = (cntb + 63) >> 6;
  const bool lo32 = (lane < 32);

  // Q as QKT B-operand: qf[qi][kk] = Q[q0+qi*16+c][kk*32+g*8 ..+8] (pre-scaled)
  short8 qf[2][2];
#pragma unroll
  for (int qi = 0; qi < 2; qi++)
#pragma unroll
    for (int kk = 0; kk < 2; kk++)
      qf[qi][kk] = *(const short8*)(Qb + (q0 + qi * 16 + c) * 64 + kk * 32 + g * 8);

  f32x4 oacc[4][2] = {};          // O^T frag: [dmi][qi], reg r -> d=16dmi+4g+r, q=16qi+c
  float mrun[2], lrun[2];
  mrun[0] = mrun[1] = -__builtin_inff();
  lrun[0] = lrun[1] = 0.f;

  const int srow = t >> 3, sch = t & 7;   // staging: row in [0,32), chunk in [0,8)
  const int swzw = sch << 3;              // Vt write swizzle ((d>>3)<<3)

#define K_STAGE(bsel, k0v)                                                    \
  {                                                                           \
    _Pragma("unroll") for (int p = 0; p < 2; p++) {                           \
      const int row = p * 32 + srow;                                          \
      const int gc8 = ((sch ^ (row & 7)) * 8);                                \
      gload16(Kb + (size_t)((k0v) + row) * 64 + gc8,                          \
              (char*)&Ks[bsel][0][0] + p * 4096 + (t >> 6) * 1024);           \
    }                                                                         \
  }

  // prologue: K tile0 via DMA; V tile0 via regs + transposed LDS writes
  K_STAGE(0, 0);
  {
    short8 v0a = *(const short8*)(Vb + (size_t)srow * 64 + sch * 8);
    short8 v1a = *(const short8*)(Vb + (size_t)(srow + 32) * 64 + sch * 8);
#pragma unroll
    for (int j = 0; j < 8; j++) {
      Vt[0][sch * 8 + j][srow ^ swzw] = v0a[j];
      Vt[0][sch * 8 + j][(srow + 32) ^ swzw] = v1a[j];
    }
  }

  for (int it = 0; it < ntiles; ++it) {
    const int bd = it & 1;
    const int k0 = it * 64;
    __syncthreads();                 // K gload(bd) + Vt(bd) writes complete
    short8 nv0, nv1;
    if (it + 1 < ntiles) {
      K_STAGE(bd ^ 1, k0 + 64);
      nv0 = *(const short8*)(Vb + (size_t)(k0 + 64 + srow) * 64 + sch * 8);
      nv1 = *(const short8*)(Vb + (size_t)(k0 + 64 + srow + 32) * 64 + sch * 8);
    }

    // S^T = K Q^T (log2 domain)
    f32x4 st[2][4];
    __builtin_amdgcn_s_setprio(1);
#pragma unroll
    for (int mi = 0; mi < 4; mi++) {
      short8 ka0 = *(const short8*)&Ks[bd][mi * 16 + c][(g ^ (c & 7)) * 8];
      short8 ka1 = *(const short8*)&Ks[bd][mi * 16 + c][((4 + g) ^ (c & 7)) * 8];
#pragma unroll
      for (int qi = 0; qi < 2; qi++) {
        f32x4 zz = {0.f, 0.f, 0.f, 0.f};
        zz = mfma_bf16(ka0, qf[qi][0], zz);
        zz = mfma_bf16(ka1, qf[qi][1], zz);
        st[qi][mi] = zz;
      }
    }
    __builtin_amdgcn_s_setprio(0);
    // pad bias only on the last partial tile; slot = k0+16mi+4g+r
    if (k0 + 64 > cntb) {
#pragma unroll
      for (int mi = 0; mi < 4; mi++)
#pragma unroll
        for (int r = 0; r < 4; r++) {
          const float pb = (k0 + 16 * mi + 4 * g + r >= cntb) ? NEGB2 : 0.f;
          st[0][mi][r] += pb;
          st[1][mi][r] += pb;
        }
    }
    // row max (tree) + cross-group shfl
    float pm[2];
#pragma unroll
    for (int qi = 0; qi < 2; qi++) {
      float a0 = fmaxf(fmaxf(st[qi][0][0], st[qi][0][1]),
                       fmaxf(st[qi][0][2], st[qi][0][3]));
      float a1 = fmaxf(fmaxf(st[qi][1][0], st[qi][1][1]),
                       fmaxf(st[qi][1][2], st[qi][1][3]));
      float a2 = fmaxf(fmaxf(st[qi][2][0], st[qi][2][1]),
                       fmaxf(st[qi][2][2], st[qi][2][3]));
      float a3 = fmaxf(fmaxf(st[qi][3][0], st[qi][3][1]),
                       fmaxf(st[qi][3][2], st[qi][3][3]));
      float x = fmaxf(fmaxf(a0, a1), fmaxf(a2, a3));
      x = fmaxf(x, __shfl_xor(x, 16));
      x = fmaxf(x, __shfl_xor(x, 32));
      pm[qi] = x;
    }
    // defer-max (T13)
    if (!__all((pm[0] <= mrun[0] + THR2) && (pm[1] <= mrun[1] + THR2))) {
#pragma unroll
      for (int qi = 0; qi < 2; qi++) {
        float mnew = fmaxf(mrun[qi], pm[qi]);
        float al = __builtin_amdgcn_exp2f(mrun[qi] - mnew);
        mrun[qi] = mnew;
        lrun[qi] *= al;
#pragma unroll
        for (int dmi = 0; dmi < 4; dmi++)
#pragma unroll
          for (int r = 0; r < 4; r++) oacc[dmi][qi][r] *= al;
      }
    }
    // P = exp2(st - m), tree row-sum, pack to bf16 (in registers)
    unsigned uu[2][4][2];
#pragma unroll
    for (int qi = 0; qi < 2; qi++) {
      float s4[4];
#pragma unroll
      for (int mi = 0; mi < 4; mi++) {
#pragma unroll
        for (int r = 0; r < 4; r++)
          st[qi][mi][r] = __builtin_amdgcn_exp2f(st[qi][mi][r] - mrun[qi]);
        s4[mi] = (st[qi][mi][0] + st[qi][mi][1]) + (st[qi][mi][2] + st[qi][mi][3]);
      }
      float ps = (s4[0] + s4[1]) + (s4[2] + s4[3]);
      ps += __shfl_xor(ps, 16);
      ps += __shfl_xor(ps, 32);
      lrun[qi] += ps;
#pragma unroll
      for (int mi = 0; mi < 4; mi++) {
        asm("v_cvt_pk_bf16_f32 %0, %1, %2"
            : "=v"(uu[qi][mi][0]) : "v"(st[qi][mi][0]), "v"(st[qi][mi][1]));
        asm("v_cvt_pk_bf16_f32 %0, %1, %2"
            : "=v"(uu[qi][mi][1]) : "v"(st[qi][mi][2]), "v"(st[qi][mi][3]));
      }
    }
    // PV: O^T += Vt . P^T. B-frag built in VALU via permlane swaps (verified R9).
#pragma unroll
    for (int kk = 0; kk < 2; kk++) {
      short8 pb[2];
#pragma unroll
      for (int qi = 0; qi < 2; qi++) {
        i32x4 dw;
#pragma unroll
        for (int x = 0; x < 2; x++) {
          unsigned pa = uu[qi][2 * kk][x], qa = pa;
          asm("v_permlane32_swap_b32 %0, %1" : "+v"(pa), "+v"(qa));
          asm("v_permlane16_swap_b32 %0, %1" : "+v"(pa), "+v"(qa));
          unsigned pbr = uu[qi][2 * kk + 1][x], qbr = pbr;
          asm("v_permlane32_swap_b32 %0, %1" : "+v"(pbr), "+v"(qbr));
          asm("v_permlane16_swap_b32 %0, %1" : "+v"(pbr), "+v"(qbr));
          dw[x]     = (int)(lo32 ? pa : pbr);
          dw[2 + x] = (int)(lo32 ? qa : qbr);
        }
        pb[qi] = __builtin_bit_cast(short8, dw);
      }
      __builtin_amdgcn_s_setprio(1);
#pragma unroll
      for (int dmi = 0; dmi < 4; dmi++) {
        const int hsw = ((2 * dmi + (c >> 3)) & 7) << 3;
        short8 vf = *(const short8*)&Vt[bd][16 * dmi + c][(32 * kk + 8 * g) ^ hsw];
        oacc[dmi][0] = mfma_bf16(vf, pb[0], oacc[dmi][0]);
        oacc[dmi][1] = mfma_bf16(vf, pb[1], oacc[dmi][1]);
      }
      __builtin_amdgcn_s_setprio(0);
    }
    // write next V tile into other buffer (before the loop-top barrier)
    if (it + 1 < ntiles) {
#pragma unroll
      for (int j = 0; j < 8; j++) {
        Vt[bd ^ 1][sch * 8 + j][srow ^ swzw] = nv0[j];
        Vt[bd ^ 1][sch * 8 + j][(srow + 32) ^ swzw] = nv1[j];
      }
    }
  }
#undef K_STAGE
  // epilogue: O^T -> ctx[b][q][h*64+d]
#pragma unroll
  for (int qi = 0; qi < 2; qi++) {
    const float inv = 1.f / lrun[qi];
    const int row = q0 + qi * 16 + c;
#pragma unroll
    for (int dmi = 0; dmi < 4; dmi++) {
      float x0 = oacc[dmi][qi][0] * inv, x1 = oacc[dmi][qi][1] * inv;
      float x2 = oacc[dmi][qi][2] * inv, x3 = oacc[dmi][qi][3] * inv;
      unsigned p0, p1;
      asm("v_cvt_pk_bf16_f32 %0, %1, %2" : "=v"(p0) : "v"(x0), "v"(x1));
      asm("v_cvt_pk_bf16_f32 %0, %1, %2" : "=v"(p1) : "v"(x2), "v"(x3));
      uint2 u2v; u2v.x = p0; u2v.y = p1;
      *(uint2*)&ctx[(size_t)(b * S_LEN + row) * 768 + h * 64 + 16 * dmi + 4 * g] = u2v;
    }
  }
}

// ---------------- launch ----------------
extern "C" void kernel_launch(void* const* d_in, const int* in_sizes, int n_in,
                              void* d_out, int out_size, void* d_ws, size_t ws_size,
                              hipStream_t stream) {
  const float* x  = (const float*)d_in[0];
  const int* mask = (const int*)d_in[1];
  const float* Wq = (const float*)d_in[2];
  const float* bq = (const float*)d_in[3];
  const float* Wk = (const float*)d_in[4];
  const float* bk = (const float*)d_in[5];
  const float* Wv = (const float*)d_in[6];
  const float* bv = (const float*)d_in[7];
  const float* Wo = (const float*)d_in[8];
  const float* bo = (const float*)d_in[9];
  float* out = (float*)d_out;

  const int NE = 8192 * 768;
  const int WE = 768 * 768;
  unsigned short* ws   = (unsigned short*)d_ws;
  unsigned short* xb   = ws;               // x bf16 [8192][768]
  unsigned short* wqkv = xb + NE;          // [2304][768]
  unsigned short* wob  = wqkv + 3 * WE;    // [768][768] (contiguous after wqkv)
  unsigned short* qb   = wob + WE;         // Q | Kc | Vc each [BH][4096][64]
  unsigned short* ctxb = qb + 3 * NE;      // ctx bf16 [8192][768]
  int* pos = (int*)(ctxb + NE);            // [2][4096]
  int* cnt = pos + 2 * S_LEN;              // [2]

  mask_scan<<<dim3(2), 64, 0, stream>>>(mask, pos, cnt);
  cvt_kernel<<<dim3(2048), 256, 0, stream>>>(x, xb, NE / 8);
  cvt_w4_kernel<<<dim3(288, 4), 256, 0, stream>>>(Wq, Wk, Wv, Wo, wqkv, WE / 8);

  gemm_bt<0><<<dim3(18, 64), 256, 0, stream>>>(xb, wqkv, 768, bq, bk, bv, pos,
                                               qb, nullptr);
  attn_kernel<<<dim3(32, 24), 256, 0, stream>>>(qb, qb + NE, qb + 2 * NE, cnt, ctxb);
  gemm_bt<1><<<dim3(6, 64), 256, 0, stream>>>(ctxb, wob, 768, bo, nullptr, nullptr,
                                              nullptr, nullptr, out);
}